// Round 8
// baseline (839.998 us; speedup 1.0000x reference)
//
#include <hip/hip_runtime.h>
#include <hip/hip_bf16.h>

typedef __attribute__((ext_vector_type(8))) short short8;
typedef __attribute__((ext_vector_type(4))) float f32x4;
typedef unsigned short u16;
typedef unsigned int u32;

#define NTOK   8192
#define DMODEL 1024
#define DFF    4096
#define NEXP   8
#define NPAIR  (NTOK * 2)
#define PADM   256            // per-expert padding
#define MT1    72             // ceil((16384 + 8*255)/256)
#define PPAD   (MT1 * PADM)   // 18432

// ---- workspace layout (bytes) ----
#define OFF_XB   0ull
#define OFF_W1T  (OFF_XB  + (size_t)NTOK * DMODEL * 2)
#define OFF_W2T  (OFF_W1T + (size_t)NEXP * DFF * DMODEL * 2)
#define OFF_W3T  (OFF_W2T + (size_t)NEXP * DFF * DMODEL * 2)
#define OFF_H    (OFF_W3T + (size_t)NEXP * DMODEL * DFF * 2)
#define OFF_TOK  (OFF_H   + (size_t)PPAD * DFF * 2)
#define OFF_WGT  (OFF_TOK + (size_t)PPAD * 4)
#define OFF_CNT  (OFF_WGT + (size_t)PPAD * 4)
#define OFF_CUR  (OFF_CNT + 64)
#define OFF_OFFP (OFF_CUR + 64)
#define WS_END   (OFF_OFFP + 64)

#define GLOAD16(gp, lp)                                                        \
  __builtin_amdgcn_global_load_lds(                                            \
      (const __attribute__((address_space(1))) u32*)(gp),                      \
      (__attribute__((address_space(3))) u32*)(lp), 16, 0, 0)

__device__ __forceinline__ u16 f2bu(float f) {
  __hip_bfloat16 b = __float2bfloat16(f);
  return __builtin_bit_cast(u16, b);
}

// ---------------- conversion kernels ----------------

__global__ __launch_bounds__(256) void cvt_x_k(const float* __restrict__ x,
                                               u16* __restrict__ xb) {
  int i = blockIdx.x * 256 + threadIdx.x;
  float4 v = ((const float4*)x)[i];
  unsigned long long pk = (unsigned long long)f2bu(v.x) |
                          ((unsigned long long)f2bu(v.y) << 16) |
                          ((unsigned long long)f2bu(v.z) << 32) |
                          ((unsigned long long)f2bu(v.w) << 48);
  ((unsigned long long*)xb)[i] = pk;
}

// transpose [R][C] fp32 -> [C][R] bf16, batched over blockIdx.z
__global__ __launch_bounds__(256) void tr_cvt_k(const float* __restrict__ src,
                                                u16* __restrict__ dst, int R, int C) {
  src += (size_t)blockIdx.z * R * C;
  dst += (size_t)blockIdx.z * R * C;
  int c0 = blockIdx.x * 64, r0 = blockIdx.y * 64;
  __shared__ float tile[64][65];
  int tid = threadIdx.x;
  int f4 = tid & 15, rr = tid >> 4;
#pragma unroll
  for (int p = 0; p < 4; ++p) {
    int r = rr + p * 16;
    float4 v = *(const float4*)(src + (size_t)(r0 + r) * C + c0 + f4 * 4);
    tile[r][f4 * 4 + 0] = v.x; tile[r][f4 * 4 + 1] = v.y;
    tile[r][f4 * 4 + 2] = v.z; tile[r][f4 * 4 + 3] = v.w;
  }
  __syncthreads();
  int ch = tid & 7, cc = tid >> 3;
#pragma unroll
  for (int p = 0; p < 2; ++p) {
    int c = cc + p * 32;
    short8 s;
#pragma unroll
    for (int j = 0; j < 8; ++j) s[j] = (short)f2bu(tile[ch * 8 + j][c]);
    *(short8*)(dst + (size_t)(c0 + c) * R + r0 + ch * 8) = s;
  }
}

// ---------------- routing kernels ----------------

__global__ __launch_bounds__(256) void count_k(const int* __restrict__ ei,
                                               int* __restrict__ cnt) {
  int i = blockIdx.x * 256 + threadIdx.x;
  atomicAdd(&cnt[ei[i]], 1);
}

__global__ void scan_k(const int* __restrict__ cnt, int* __restrict__ offp) {
  if (threadIdx.x == 0) {
    int a = 0;
#pragma unroll
    for (int e = 0; e < NEXP; ++e) { offp[e] = a; a += (cnt[e] + PADM - 1) & ~(PADM - 1); }
    offp[NEXP] = a;
  }
}

__global__ __launch_bounds__(256) void scatter_k(const int* __restrict__ ei,
                                                 const float* __restrict__ ew,
                                                 const int* __restrict__ offp,
                                                 int* __restrict__ cur,
                                                 int* __restrict__ tok,
                                                 float* __restrict__ wg) {
  int i = blockIdx.x * 256 + threadIdx.x;
  int e = ei[i];
  int p = offp[e] + atomicAdd(&cur[e], 1);
  tok[p] = i >> 1;
  wg[p] = ew[i];
}

// ---------------- stage 1: h = silu(x@W1) * (x@W2), grouped ----------------
// BK=64, 2-buffer (2 x 64 KB LDS), 16 K-steps, ONE barrier per step.
// Per step: issue all 8 next-buffer global_load_lds FIRST (legal: other
// buffer, previous barrier passed), then 24 ds_read_b128 + 64 MFMA per wave
// (kk-outer to cap live frags at 12 short8), then vmcnt(0) (loads had the
// whole ~4000-cyc step to land) + s_barrier. 8-slot seg^(row&7) swizzle
// (r1-measured 0 conflicts at BK=64).

#define S1_BUF 32768   // u16 per buffer: A 16384 | B1 8192 | B2 8192 (64 KB)
#define S1_NK  16      // 1024 / 64

__global__ __launch_bounds__(512, 2) void stage1_k(const u16* __restrict__ xb,
                                                   const u16* __restrict__ w1t,
                                                   const u16* __restrict__ w2t,
                                                   u16* __restrict__ h,
                                                   const int* __restrict__ tok,
                                                   const int* __restrict__ offp) {
  extern __shared__ __align__(16) u16 lds[];   // 2 * 64 KB = 131072 B
  const int r0 = blockIdx.y * PADM;
  if (r0 >= offp[NEXP]) return;
  int e = 0;
#pragma unroll
  for (int q = 0; q < 7; ++q) e += (offp[e + 1] <= r0) ? 1 : 0;
  const int n0 = blockIdx.x * 128;
  const int tid = threadIdx.x;
  const int lane = tid & 63, w = tid >> 6;
  const int wm = w >> 2, wn = w & 3;
  const int lr = lane >> 3, seg = lane & 7;

  // ---- staging source pointers (per-lane, source-side XOR swizzle) ----
  const u16* aga[4];
  int adb[4];
#pragma unroll
  for (int j = 0; j < 4; ++j) {
    int row = w * 32 + j * 8 + lr;
    int t = tok[r0 + row];
    aga[j] = xb + (size_t)t * DMODEL + ((seg ^ (row & 7)) << 3);
    adb[j] = (w * 32 + j * 8) * 64;
  }
  const u16* w1e = w1t + (size_t)e * DFF * DMODEL;
  const u16* w2e = w2t + (size_t)e * DFF * DMODEL;
  const u16* bg1[2]; const u16* bg2[2];
  int bdb[2];
#pragma unroll
  for (int j = 0; j < 2; ++j) {
    int row = w * 16 + j * 8 + lr;               // B tile row = ff-col offset
    size_t ro = (size_t)(n0 + row) * DMODEL + ((seg ^ (row & 7)) << 3);
    bg1[j] = w1e + ro; bg2[j] = w2e + ro;
    bdb[j] = (w * 16 + j * 8) * 64;
  }

  // ---- fragment read offsets (u16 idx) ----
  int aoff[8][2], boff[2][2];
  {
    int ks = lane >> 4;
#pragma unroll
    for (int mi = 0; mi < 8; ++mi)
#pragma unroll
      for (int kk = 0; kk < 2; ++kk) {
        int row = wm * 128 + mi * 16 + (lane & 15);
        aoff[mi][kk] = row * 64 + (((kk * 4 + ks) ^ (row & 7)) << 3);
      }
#pragma unroll
    for (int ni = 0; ni < 2; ++ni)
#pragma unroll
      for (int kk = 0; kk < 2; ++kk) {
        int col = wn * 32 + ni * 16 + (lane & 15);
        boff[ni][kk] = col * 64 + (((kk * 4 + ks) ^ (col & 7)) << 3);
      }
  }

  f32x4 accg[8][2], accv[8][2];
  const f32x4 zero = {0.f, 0.f, 0.f, 0.f};
#pragma unroll
  for (int mi = 0; mi < 8; ++mi)
#pragma unroll
    for (int ni = 0; ni < 2; ++ni) { accg[mi][ni] = zero; accv[mi][ni] = zero; }

#define S1_ISSUE(Q, KO)                                                        \
  do {                                                                         \
    GLOAD16(aga[0] + (KO), (Q) + adb[0]);                                      \
    GLOAD16(aga[1] + (KO), (Q) + adb[1]);                                      \
    GLOAD16(aga[2] + (KO), (Q) + adb[2]);                                      \
    GLOAD16(aga[3] + (KO), (Q) + adb[3]);                                      \
    GLOAD16(bg1[0] + (KO), (Q) + 16384 + bdb[0]);                              \
    GLOAD16(bg1[1] + (KO), (Q) + 16384 + bdb[1]);                              \
    GLOAD16(bg2[0] + (KO), (Q) + 24576 + bdb[0]);                              \
    GLOAD16(bg2[1] + (KO), (Q) + 24576 + bdb[1]);                              \
  } while (0)

  // ---- prologue: stage K-step 0 into buffer 0 ----
  S1_ISSUE(lds, 0);
  asm volatile("s_waitcnt vmcnt(0)" ::: "memory");
  __builtin_amdgcn_s_barrier();
  __builtin_amdgcn_sched_barrier(0);

#define S1_STEP(P, KC, ISSUE)                                                  \
  {                                                                            \
    const u16* Ab  = lds + (P) * S1_BUF;                                       \
    const u16* B1b = Ab + 16384;                                               \
    const u16* B2b = Ab + 24576;                                               \
    if (ISSUE) S1_ISSUE(lds + (1 - (P)) * S1_BUF, ((KC) + 1) * 64);            \
    _Pragma("unroll") for (int kk = 0; kk < 2; ++kk) {                         \
      short8 af[8], b1f[2], b2f[2];                                            \
      _Pragma("unroll") for (int mi = 0; mi < 8; ++mi)                         \
        af[mi] = *(const short8*)(Ab + aoff[mi][kk]);                          \
      _Pragma("unroll") for (int ni = 0; ni < 2; ++ni) {                       \
        b1f[ni] = *(const short8*)(B1b + boff[ni][kk]);                        \
        b2f[ni] = *(const short8*)(B2b + boff[ni][kk]);                        \
      }                                                                        \
      __builtin_amdgcn_s_setprio(1);                                           \
      _Pragma("unroll") for (int mi = 0; mi < 8; ++mi)                         \
        _Pragma("unroll") for (int ni = 0; ni < 2; ++ni) {                     \
          accg[mi][ni] = __builtin_amdgcn_mfma_f32_16x16x32_bf16(              \
              af[mi], b1f[ni], accg[mi][ni], 0, 0, 0);                         \
          accv[mi][ni] = __builtin_amdgcn_mfma_f32_16x16x32_bf16(              \
              af[mi], b2f[ni], accv[mi][ni], 0, 0, 0);                         \
        }                                                                      \
      __builtin_amdgcn_s_setprio(0);                                           \
    }                                                                          \
    asm volatile("s_waitcnt vmcnt(0)" ::: "memory");                           \
    __builtin_amdgcn_s_barrier();                                              \
    __builtin_amdgcn_sched_barrier(0);                                         \
  }

  for (int kc = 0; kc < S1_NK - 2; kc += 2) {
    S1_STEP(0, kc, 1)
    S1_STEP(1, kc + 1, 1)
  }
  S1_STEP(0, S1_NK - 2, 1)
  S1_STEP(1, S1_NK - 1, 0)
#undef S1_STEP
#undef S1_ISSUE

  // ---- epilogue: silu(gate) * val -> h ----
  const int prow = r0 + wm * 128 + ((lane >> 4) << 2);
  const int pcol = n0 + wn * 32 + (lane & 15);
#pragma unroll
  for (int mi = 0; mi < 8; ++mi)
#pragma unroll
    for (int ni = 0; ni < 2; ++ni)
#pragma unroll
      for (int j = 0; j < 4; ++j) {
        float g = accg[mi][ni][j];
        float v = accv[mi][ni][j];
        float s = g / (1.f + __expf(-g));
        h[(size_t)(prow + mi * 16 + j) * DFF + (pcol + ni * 16)] = f2bu(s * v);
      }
}

// ---------------- stage 2: out += p * (h @ W3), grouped ----------------
// r7 structure kept: 3-buffer counted-vmcnt, BK=64, tile 256x128, 512 thr.

#define S2_BUF 24576   // u16 per buffer: A 16384 (256x64) | B 8192 (128x64)
#define S2_NK  64      // 4096 / 64

__global__ __launch_bounds__(512, 2) void stage2_k(const u16* __restrict__ h,
                                                   const u16* __restrict__ w3t,
                                                   float* __restrict__ out,
                                                   const int* __restrict__ tok,
                                                   const float* __restrict__ wg,
                                                   const int* __restrict__ offp) {
  extern __shared__ __align__(16) u16 lds[];   // 3 * 49152 B = 147456 B
  const int r0 = blockIdx.y * 256;
  if (r0 >= offp[NEXP]) return;
  int e = 0;
#pragma unroll
  for (int q = 0; q < 7; ++q) e += (offp[e + 1] <= r0) ? 1 : 0;
  const int n0 = blockIdx.x * 128;
  const int tid = threadIdx.x;
  const int lane = tid & 63, w = tid >> 6;
  const int wm = w >> 1, wn = w & 1;
  const int lr = lane >> 3, seg = lane & 7;

  const u16* aga[4];
  int adb[4];
#pragma unroll
  for (int j = 0; j < 4; ++j) {
    int row = w * 32 + j * 8 + lr;
    aga[j] = h + (size_t)(r0 + row) * DFF + ((seg ^ (row & 7)) << 3);
    adb[j] = (w * 32 + j * 8) * 64;
  }
  const u16* w3e = w3t + (size_t)e * DMODEL * DFF;
  const u16* bga[2];
  int bdb[2];
#pragma unroll
  for (int j = 0; j < 2; ++j) {
    int row = w * 16 + j * 8 + lr;
    bga[j] = w3e + (size_t)(n0 + row) * DFF + ((seg ^ (row & 7)) << 3);
    bdb[j] = (w * 16 + j * 8) * 64;
  }

  int aoff[4][2], boff[4][2];
  {
    int ks = lane >> 4;
#pragma unroll
    for (int mi = 0; mi < 4; ++mi)
#pragma unroll
      for (int kk = 0; kk < 2; ++kk) {
        int row = wm * 64 + mi * 16 + (lane & 15);
        aoff[mi][kk] = row * 64 + (((kk * 4 + ks) ^ (row & 7)) << 3);
      }
#pragma unroll
    for (int ni = 0; ni < 4; ++ni)
#pragma unroll
      for (int kk = 0; kk < 2; ++kk) {
        int col = wn * 64 + ni * 16 + (lane & 15);
        boff[ni][kk] = col * 64 + (((kk * 4 + ks) ^ (col & 7)) << 3);
      }
  }

  f32x4 acc[4][4];
  const f32x4 zero = {0.f, 0.f, 0.f, 0.f};
#pragma unroll
  for (int mi = 0; mi < 4; ++mi)
#pragma unroll
    for (int ni = 0; ni < 4; ++ni) acc[mi][ni] = zero;

#define S2_ISSUE(Q, KO)                                                        \
  do {                                                                         \
    GLOAD16(aga[0] + (KO), (Q) + adb[0]);                                      \
    GLOAD16(aga[1] + (KO), (Q) + adb[1]);                                      \
    GLOAD16(aga[2] + (KO), (Q) + adb[2]);                                      \
    GLOAD16(aga[3] + (KO), (Q) + adb[3]);                                      \
    GLOAD16(bga[0] + (KO), (Q) + 16384 + bdb[0]);                              \
    GLOAD16(bga[1] + (KO), (Q) + 16384 + bdb[1]);                              \
  } while (0)

  S2_ISSUE(lds, 0);
  S2_ISSUE(lds + S2_BUF, 64);
  asm volatile("s_waitcnt vmcnt(6)" ::: "memory");
  __builtin_amdgcn_s_barrier();
  __builtin_amdgcn_sched_barrier(0);

#define S2_STEP(P, KC, ISSUE)                                                  \
  {                                                                            \
    const u16* Ab = lds + (P) * S2_BUF;                                        \
    const u16* Bb = Ab + 16384;                                                \
    short8 af[4][2], bf[4][2];                                                 \
    _Pragma("unroll") for (int mi = 0; mi < 4; ++mi)                           \
      _Pragma("unroll") for (int kk = 0; kk < 2; ++kk)                         \
        af[mi][kk] = *(const short8*)(Ab + aoff[mi][kk]);                      \
    _Pragma("unroll") for (int ni = 0; ni < 4; ++ni)                           \
      _Pragma("unroll") for (int kk = 0; kk < 2; ++kk)                         \
        bf[ni][kk] = *(const short8*)(Bb + boff[ni][kk]);                      \
    if (ISSUE) S2_ISSUE(lds + (((P) + 2) % 3) * S2_BUF, ((KC) + 2) * 64);      \
    __builtin_amdgcn_s_setprio(1);                                             \
    _Pragma("unroll") for (int kk = 0; kk < 2; ++kk)                           \
      _Pragma("unroll") for (int mi = 0; mi < 4; ++mi)                         \
        _Pragma("unroll") for (int ni = 0; ni < 4; ++ni)                       \
          acc[mi][ni] = __builtin_amdgcn_mfma_f32_16x16x32_bf16(               \
              af[mi][kk], bf[ni][kk], acc[mi][ni], 0, 0, 0);                   \
    __builtin_amdgcn_s_setprio(0);                                             \
    if (ISSUE) asm volatile("s_waitcnt vmcnt(6)" ::: "memory");                \
    else       asm volatile("s_waitcnt vmcnt(0)" ::: "memory");                \
    __builtin_amdgcn_s_barrier();                                              \
    __builtin_amdgcn_sched_barrier(0);                                         \
  }

  for (int kc = 0; kc < S2_NK - 4; kc += 3) {
    S2_STEP(0, kc, 1)
    S2_STEP(1, kc + 1, 1)
    S2_STEP(2, kc + 2, 1)
  }
  S2_STEP(0, S2_NK - 4, 1)
  S2_STEP(1, S2_NK - 3, 1)
  S2_STEP(2, S2_NK - 2, 0)
  S2_STEP(0, S2_NK - 1, 0)
#undef S2_STEP
#undef S2_ISSUE

  const int prow = r0 + wm * 64 + ((lane >> 4) << 2);
  const int pcolb = n0 + wn * 64 + (lane & 15);
#pragma unroll
  for (int mi = 0; mi < 4; ++mi)
#pragma unroll
    for (int j = 0; j < 4; ++j) {
      int pos = prow + mi * 16 + j;
      float p = wg[pos];
      if (p != 0.f) {
        int t = tok[pos];
#pragma unroll
        for (int ni = 0; ni < 4; ++ni)
          atomicAdd(&out[(size_t)t * DMODEL + pcolb + ni * 16], p * acc[mi][ni][j]);
      }
    }
}

// ---------------- launch ----------------

extern "C" void kernel_launch(void* const* d_in, const int* in_sizes, int n_in,
                              void* d_out, int out_size, void* d_ws, size_t ws_size,
                              hipStream_t stream) {
  (void)in_sizes; (void)n_in;
  const float* x  = (const float*)d_in[0];
  const int*   ei = (const int*)d_in[1];
  const float* ew = (const float*)d_in[2];
  const float* w1 = (const float*)d_in[3];
  const float* w2 = (const float*)d_in[4];
  const float* w3 = (const float*)d_in[5];
  float* out = (float*)d_out;
  char* ws = (char*)d_ws;

  hipMemsetAsync(out, 0, (size_t)out_size * sizeof(float), stream);
  if (ws_size < WS_END) return;   // ws too small: leave zeros (diagnosable absmax)

  u16* xb   = (u16*)(ws + OFF_XB);
  u16* w1t  = (u16*)(ws + OFF_W1T);
  u16* w2t  = (u16*)(ws + OFF_W2T);
  u16* w3t  = (u16*)(ws + OFF_W3T);
  u16* hb   = (u16*)(ws + OFF_H);
  int* tok  = (int*)(ws + OFF_TOK);
  float* wg = (float*)(ws + OFF_WGT);
  int* cnt  = (int*)(ws + OFF_CNT);
  int* cur  = (int*)(ws + OFF_CUR);
  int* offp = (int*)(ws + OFF_OFFP);

  hipMemsetAsync(ws + OFF_TOK, 0, (size_t)(WS_END - OFF_TOK), stream);

  hipFuncSetAttribute(reinterpret_cast<const void*>(stage1_k),
                      hipFuncAttributeMaxDynamicSharedMemorySize, 131072);
  hipFuncSetAttribute(reinterpret_cast<const void*>(stage2_k),
                      hipFuncAttributeMaxDynamicSharedMemorySize, 147456);

  cvt_x_k<<<dim3(NTOK * DMODEL / 4 / 256), 256, 0, stream>>>(x, xb);
  tr_cvt_k<<<dim3(DFF / 64, DMODEL / 64, NEXP), 256, 0, stream>>>(w1, w1t, DMODEL, DFF);
  tr_cvt_k<<<dim3(DFF / 64, DMODEL / 64, NEXP), 256, 0, stream>>>(w2, w2t, DMODEL, DFF);
  tr_cvt_k<<<dim3(DMODEL / 64, DFF / 64, NEXP), 256, 0, stream>>>(w3, w3t, DFF, DMODEL);
  count_k<<<dim3(NPAIR / 256), 256, 0, stream>>>(ei, cnt);
  scan_k<<<1, 64, 0, stream>>>(cnt, offp);
  scatter_k<<<dim3(NPAIR / 256), 256, 0, stream>>>(ei, ew, offp, cur, tok, wg);
  stage1_k<<<dim3(DFF / 128, MT1), 512, 131072, stream>>>(xb, w1t, w2t, hb, tok, offp);
  stage2_k<<<dim3(DMODEL / 128, PPAD / 256), 512, 147456, stream>>>(hb, w3t, out, tok, wg, offp);
}

// Round 9
// 834.006 us; speedup vs baseline: 1.0072x; 1.0072x over previous
//
#include <hip/hip_runtime.h>
#include <hip/hip_bf16.h>

typedef __attribute__((ext_vector_type(8))) short short8;
typedef __attribute__((ext_vector_type(4))) float f32x4;
typedef unsigned short u16;
typedef unsigned int u32;

#define NTOK   8192
#define DMODEL 1024
#define DFF    4096
#define NEXP   8
#define NPAIR  (NTOK * 2)
#define PADM   256            // per-expert padding
#define MT1    72             // ceil((16384 + 8*255)/256)
#define PPAD   (MT1 * PADM)   // 18432

// ---- workspace layout (bytes) ----
#define OFF_XB   0ull
#define OFF_W1T  (OFF_XB  + (size_t)NTOK * DMODEL * 2)
#define OFF_W2T  (OFF_W1T + (size_t)NEXP * DFF * DMODEL * 2)
#define OFF_W3T  (OFF_W2T + (size_t)NEXP * DFF * DMODEL * 2)
#define OFF_H    (OFF_W3T + (size_t)NEXP * DMODEL * DFF * 2)
#define OFF_TOK  (OFF_H   + (size_t)PPAD * DFF * 2)
#define OFF_WGT  (OFF_TOK + (size_t)PPAD * 4)
#define OFF_CNT  (OFF_WGT + (size_t)PPAD * 4)
#define OFF_CUR  (OFF_CNT + 64)
#define OFF_OFFP (OFF_CUR + 64)
#define WS_END   (OFF_OFFP + 64)

#define GLOAD16(gp, lp)                                                        \
  __builtin_amdgcn_global_load_lds(                                            \
      (const __attribute__((address_space(1))) u32*)(gp),                      \
      (__attribute__((address_space(3))) u32*)(lp), 16, 0, 0)

__device__ __forceinline__ u16 f2bu(float f) {
  __hip_bfloat16 b = __float2bfloat16(f);
  return __builtin_bit_cast(u16, b);
}

// ---------------- conversion kernels ----------------

__global__ __launch_bounds__(256) void cvt_x_k(const float* __restrict__ x,
                                               u16* __restrict__ xb) {
  int i = blockIdx.x * 256 + threadIdx.x;
  float4 v = ((const float4*)x)[i];
  unsigned long long pk = (unsigned long long)f2bu(v.x) |
                          ((unsigned long long)f2bu(v.y) << 16) |
                          ((unsigned long long)f2bu(v.z) << 32) |
                          ((unsigned long long)f2bu(v.w) << 48);
  ((unsigned long long*)xb)[i] = pk;
}

// transpose [R][C] fp32 -> [C][R] bf16, batched over blockIdx.z
__global__ __launch_bounds__(256) void tr_cvt_k(const float* __restrict__ src,
                                                u16* __restrict__ dst, int R, int C) {
  src += (size_t)blockIdx.z * R * C;
  dst += (size_t)blockIdx.z * R * C;
  int c0 = blockIdx.x * 64, r0 = blockIdx.y * 64;
  __shared__ float tile[64][65];
  int tid = threadIdx.x;
  int f4 = tid & 15, rr = tid >> 4;
#pragma unroll
  for (int p = 0; p < 4; ++p) {
    int r = rr + p * 16;
    float4 v = *(const float4*)(src + (size_t)(r0 + r) * C + c0 + f4 * 4);
    tile[r][f4 * 4 + 0] = v.x; tile[r][f4 * 4 + 1] = v.y;
    tile[r][f4 * 4 + 2] = v.z; tile[r][f4 * 4 + 3] = v.w;
  }
  __syncthreads();
  int ch = tid & 7, cc = tid >> 3;
#pragma unroll
  for (int p = 0; p < 2; ++p) {
    int c = cc + p * 32;
    short8 s;
#pragma unroll
    for (int j = 0; j < 8; ++j) s[j] = (short)f2bu(tile[ch * 8 + j][c]);
    *(short8*)(dst + (size_t)(c0 + c) * R + r0 + ch * 8) = s;
  }
}

// ---------------- routing kernels ----------------

__global__ __launch_bounds__(256) void count_k(const int* __restrict__ ei,
                                               int* __restrict__ cnt) {
  int i = blockIdx.x * 256 + threadIdx.x;
  atomicAdd(&cnt[ei[i]], 1);
}

__global__ void scan_k(const int* __restrict__ cnt, int* __restrict__ offp) {
  if (threadIdx.x == 0) {
    int a = 0;
#pragma unroll
    for (int e = 0; e < NEXP; ++e) { offp[e] = a; a += (cnt[e] + PADM - 1) & ~(PADM - 1); }
    offp[NEXP] = a;
  }
}

__global__ __launch_bounds__(256) void scatter_k(const int* __restrict__ ei,
                                                 const float* __restrict__ ew,
                                                 const int* __restrict__ offp,
                                                 int* __restrict__ cur,
                                                 int* __restrict__ tok,
                                                 float* __restrict__ wg) {
  int i = blockIdx.x * 256 + threadIdx.x;
  int e = ei[i];
  int p = offp[e] + atomicAdd(&cur[e], 1);
  tok[p] = i >> 1;
  wg[p] = ew[i];
}

// ---------------- stage 1: h = silu(x@W1) * (x@W2), grouped ----------------
// r5 kernel verbatim (best measured: 321 us, MfmaUtil 40.5%, 0 conflicts).
// 3-buffer, BK=32, counted vmcnt(4), 1 barrier/step, MFMA 16x16x32.

#define S1_BUF 16384   // u16 per buffer: A 8192 | B1 4096 | B2 4096
#define S1_NK  32      // 1024 / 32

__global__ __launch_bounds__(512, 2) void stage1_k(const u16* __restrict__ xb,
                                                   const u16* __restrict__ w1t,
                                                   const u16* __restrict__ w2t,
                                                   u16* __restrict__ h,
                                                   const int* __restrict__ tok,
                                                   const int* __restrict__ offp) {
  extern __shared__ __align__(16) u16 lds[];   // 3 * 32 KB = 98304 B
  const int r0 = blockIdx.y * PADM;
  if (r0 >= offp[NEXP]) return;
  int e = 0;
#pragma unroll
  for (int q = 0; q < 7; ++q) e += (offp[e + 1] <= r0) ? 1 : 0;
  const int n0 = blockIdx.x * 128;
  const int tid = threadIdx.x;
  const int lane = tid & 63, w = tid >> 6;
  const int wm = w >> 2, wn = w & 3;

  const int sl = lane & 3, rl = lane >> 2;
  const u16* aga[2];
  int adb[2];
#pragma unroll
  for (int j = 0; j < 2; ++j) {
    int row = w * 32 + j * 16 + rl;
    int t = tok[r0 + row];
    aga[j] = xb + (size_t)t * DMODEL + ((sl ^ ((row >> 1) & 3)) << 3);
    adb[j] = (w * 32 + j * 16) * 32;
  }
  const u16* w1e = w1t + (size_t)e * DFF * DMODEL;
  const u16* w2e = w2t + (size_t)e * DFF * DMODEL;
  const u16* bg1; const u16* bg2;
  int bdb;
  {
    int row = w * 16 + rl;
    size_t ro = (size_t)(n0 + row) * DMODEL + ((sl ^ ((row >> 1) & 3)) << 3);
    bg1 = w1e + ro; bg2 = w2e + ro;
    bdb = (w * 16) * 32;
  }

  int aoff[8], boff[2];
  {
    int ks = lane >> 4;
#pragma unroll
    for (int mi = 0; mi < 8; ++mi) {
      int row = wm * 128 + mi * 16 + (lane & 15);
      aoff[mi] = row * 32 + ((ks ^ ((row >> 1) & 3)) << 3);
    }
#pragma unroll
    for (int ni = 0; ni < 2; ++ni) {
      int col = wn * 32 + ni * 16 + (lane & 15);
      boff[ni] = col * 32 + ((ks ^ ((col >> 1) & 3)) << 3);
    }
  }

  f32x4 accg[8][2], accv[8][2];
  const f32x4 zero = {0.f, 0.f, 0.f, 0.f};
#pragma unroll
  for (int mi = 0; mi < 8; ++mi)
#pragma unroll
    for (int ni = 0; ni < 2; ++ni) { accg[mi][ni] = zero; accv[mi][ni] = zero; }

#define S1_ISSUE(Q, KO)                                                        \
  do {                                                                         \
    GLOAD16(aga[0] + (KO), (Q) + adb[0]);                                      \
    GLOAD16(aga[1] + (KO), (Q) + adb[1]);                                      \
    GLOAD16(bg1 + (KO), (Q) + 8192 + bdb);                                     \
    GLOAD16(bg2 + (KO), (Q) + 12288 + bdb);                                    \
  } while (0)

  S1_ISSUE(lds, 0);
  S1_ISSUE(lds + S1_BUF, 32);
  asm volatile("s_waitcnt vmcnt(4)" ::: "memory");
  __builtin_amdgcn_s_barrier();
  __builtin_amdgcn_sched_barrier(0);

#define S1_STEP(P, KC, ISSUE)                                                  \
  {                                                                            \
    const u16* Ab  = lds + (P) * S1_BUF;                                       \
    const u16* B1b = Ab + 8192;                                                \
    const u16* B2b = Ab + 12288;                                               \
    short8 af[8], b1f[2], b2f[2];                                              \
    _Pragma("unroll") for (int mi = 0; mi < 8; ++mi)                           \
      af[mi] = *(const short8*)(Ab + aoff[mi]);                                \
    _Pragma("unroll") for (int ni = 0; ni < 2; ++ni) {                         \
      b1f[ni] = *(const short8*)(B1b + boff[ni]);                              \
      b2f[ni] = *(const short8*)(B2b + boff[ni]);                              \
    }                                                                          \
    if (ISSUE) S1_ISSUE(lds + (((P) + 2) % 3) * S1_BUF, ((KC) + 2) * 32);      \
    __builtin_amdgcn_s_setprio(1);                                             \
    _Pragma("unroll") for (int mi = 0; mi < 8; ++mi)                           \
      _Pragma("unroll") for (int ni = 0; ni < 2; ++ni) {                       \
        accg[mi][ni] = __builtin_amdgcn_mfma_f32_16x16x32_bf16(                \
            af[mi], b1f[ni], accg[mi][ni], 0, 0, 0);                           \
        accv[mi][ni] = __builtin_amdgcn_mfma_f32_16x16x32_bf16(                \
            af[mi], b2f[ni], accv[mi][ni], 0, 0, 0);                           \
      }                                                                        \
    __builtin_amdgcn_s_setprio(0);                                             \
    if (ISSUE) asm volatile("s_waitcnt vmcnt(4)" ::: "memory");                \
    else       asm volatile("s_waitcnt vmcnt(0)" ::: "memory");                \
    __builtin_amdgcn_s_barrier();                                              \
    __builtin_amdgcn_sched_barrier(0);                                         \
  }

  for (int kc = 0; kc < S1_NK - 2; kc += 3) {
    S1_STEP(0, kc, 1)
    S1_STEP(1, kc + 1, 1)
    S1_STEP(2, kc + 2, 1)
  }
  S1_STEP(0, S1_NK - 2, 0)
  S1_STEP(1, S1_NK - 1, 0)
#undef S1_STEP
#undef S1_ISSUE

  const int prow = r0 + wm * 128 + ((lane >> 4) << 2);
  const int pcol = n0 + wn * 32 + (lane & 15);
#pragma unroll
  for (int mi = 0; mi < 8; ++mi)
#pragma unroll
    for (int ni = 0; ni < 2; ++ni)
#pragma unroll
      for (int j = 0; j < 4; ++j) {
        float g = accg[mi][ni][j];
        float v = accv[mi][ni][j];
        float s = g / (1.f + __expf(-g));
        h[(size_t)(prow + mi * 16 + j) * DFF + (pcol + ni * 16)] = f2bu(s * v);
      }
}

// ---------------- stage 2: out += p * (h @ W3), grouped ----------------
// Exact r5 per-step shape transplanted: tile 256x256, BK=32, 3-buffer
// (3 x 32 KB LDS), 512 thr (8 waves = 2M x 4N, wave tile 128x64).
// Per wave-step: 12 ds_read_b128 + 32 MFMA + 4 global_load_lds issues
// + vmcnt(4) + ONE barrier -- identical counts to stage1's measured
// 2670-cyc step. Grid 4 x 72 = 288 blocks; staged traffic 1.15 GB
// (h read 4x instead of 8x).

#define S2_BUF 16384   // u16 per buffer: A 8192 (256x32) | B 8192 (256x32)
#define S2_NK  128     // 4096 / 32

__global__ __launch_bounds__(512, 2) void stage2_k(const u16* __restrict__ h,
                                                   const u16* __restrict__ w3t,
                                                   float* __restrict__ out,
                                                   const int* __restrict__ tok,
                                                   const float* __restrict__ wg,
                                                   const int* __restrict__ offp) {
  extern __shared__ __align__(16) u16 lds[];   // 3 * 32 KB = 98304 B
  const int r0 = blockIdx.y * 256;
  if (r0 >= offp[NEXP]) return;
  int e = 0;
#pragma unroll
  for (int q = 0; q < 7; ++q) e += (offp[e + 1] <= r0) ? 1 : 0;
  const int n0 = blockIdx.x * 256;
  const int tid = threadIdx.x;
  const int lane = tid & 63, w = tid >> 6;
  const int wm = w >> 2, wn = w & 3;

  const int sl = lane & 3, rl = lane >> 2;
  // A staging: 256 rows of h, 2 issues/thread
  const u16* aga[2];
  int adb[2];
#pragma unroll
  for (int j = 0; j < 2; ++j) {
    int row = w * 32 + j * 16 + rl;
    aga[j] = h + (size_t)(r0 + row) * DFF + ((sl ^ ((row >> 1) & 3)) << 3);
    adb[j] = (w * 32 + j * 16) * 32;
  }
  // B staging: 256 out-cols of w3t, 2 issues/thread
  const u16* w3e = w3t + (size_t)e * DMODEL * DFF;
  const u16* bga[2];
  int bdb[2];
#pragma unroll
  for (int j = 0; j < 2; ++j) {
    int row = w * 32 + j * 16 + rl;
    bga[j] = w3e + (size_t)(n0 + row) * DFF + ((sl ^ ((row >> 1) & 3)) << 3);
    bdb[j] = 8192 + (w * 32 + j * 16) * 32;
  }

  int aoff[8], boff[4];
  {
    int ks = lane >> 4;
#pragma unroll
    for (int mi = 0; mi < 8; ++mi) {
      int row = wm * 128 + mi * 16 + (lane & 15);
      aoff[mi] = row * 32 + ((ks ^ ((row >> 1) & 3)) << 3);
    }
#pragma unroll
    for (int ni = 0; ni < 4; ++ni) {
      int col = wn * 64 + ni * 16 + (lane & 15);
      boff[ni] = 8192 + col * 32 + ((ks ^ ((col >> 1) & 3)) << 3);
    }
  }

  f32x4 acc[8][4];
  const f32x4 zero = {0.f, 0.f, 0.f, 0.f};
#pragma unroll
  for (int mi = 0; mi < 8; ++mi)
#pragma unroll
    for (int ni = 0; ni < 4; ++ni) acc[mi][ni] = zero;

#define S2_ISSUE(Q, KO)                                                        \
  do {                                                                         \
    GLOAD16(aga[0] + (KO), (Q) + adb[0]);                                      \
    GLOAD16(aga[1] + (KO), (Q) + adb[1]);                                      \
    GLOAD16(bga[0] + (KO), (Q) + bdb[0]);                                      \
    GLOAD16(bga[1] + (KO), (Q) + bdb[1]);                                      \
  } while (0)

  S2_ISSUE(lds, 0);
  S2_ISSUE(lds + S2_BUF, 32);
  asm volatile("s_waitcnt vmcnt(4)" ::: "memory");
  __builtin_amdgcn_s_barrier();
  __builtin_amdgcn_sched_barrier(0);

#define S2_STEP(P, KC, ISSUE)                                                  \
  {                                                                            \
    const u16* Qb = lds + (P) * S2_BUF;                                        \
    short8 af[8], bf[4];                                                       \
    _Pragma("unroll") for (int mi = 0; mi < 8; ++mi)                           \
      af[mi] = *(const short8*)(Qb + aoff[mi]);                                \
    _Pragma("unroll") for (int ni = 0; ni < 4; ++ni)                           \
      bf[ni] = *(const short8*)(Qb + boff[ni]);                                \
    if (ISSUE) S2_ISSUE(lds + (((P) + 2) % 3) * S2_BUF, ((KC) + 2) * 32);      \
    __builtin_amdgcn_s_setprio(1);                                             \
    _Pragma("unroll") for (int mi = 0; mi < 8; ++mi)                           \
      _Pragma("unroll") for (int ni = 0; ni < 4; ++ni)                         \
        acc[mi][ni] = __builtin_amdgcn_mfma_f32_16x16x32_bf16(                 \
            af[mi], bf[ni], acc[mi][ni], 0, 0, 0);                             \
    __builtin_amdgcn_s_setprio(0);                                             \
    if (ISSUE) asm volatile("s_waitcnt vmcnt(4)" ::: "memory");                \
    else       asm volatile("s_waitcnt vmcnt(0)" ::: "memory");                \
    __builtin_amdgcn_s_barrier();                                              \
    __builtin_amdgcn_sched_barrier(0);                                         \
  }

  for (int kc = 0; kc < S2_NK - 2; kc += 3) {
    S2_STEP(0, kc, 1)
    S2_STEP(1, kc + 1, 1)
    S2_STEP(2, kc + 2, 1)
  }
  S2_STEP(0, S2_NK - 2, 0)
  S2_STEP(1, S2_NK - 1, 0)
#undef S2_STEP
#undef S2_ISSUE

  const int prow = r0 + wm * 128 + ((lane >> 4) << 2);
  const int pcolb = n0 + wn * 64 + (lane & 15);
#pragma unroll
  for (int mi = 0; mi < 8; ++mi)
#pragma unroll
    for (int j = 0; j < 4; ++j) {
      int pos = prow + mi * 16 + j;
      float p = wg[pos];
      if (p != 0.f) {
        int t = tok[pos];
#pragma unroll
        for (int ni = 0; ni < 4; ++ni)
          atomicAdd(&out[(size_t)t * DMODEL + pcolb + ni * 16], p * acc[mi][ni][j]);
      }
    }
}

// ---------------- launch ----------------

extern "C" void kernel_launch(void* const* d_in, const int* in_sizes, int n_in,
                              void* d_out, int out_size, void* d_ws, size_t ws_size,
                              hipStream_t stream) {
  (void)in_sizes; (void)n_in;
  const float* x  = (const float*)d_in[0];
  const int*   ei = (const int*)d_in[1];
  const float* ew = (const float*)d_in[2];
  const float* w1 = (const float*)d_in[3];
  const float* w2 = (const float*)d_in[4];
  const float* w3 = (const float*)d_in[5];
  float* out = (float*)d_out;
  char* ws = (char*)d_ws;

  hipMemsetAsync(out, 0, (size_t)out_size * sizeof(float), stream);
  if (ws_size < WS_END) return;   // ws too small: leave zeros (diagnosable absmax)

  u16* xb   = (u16*)(ws + OFF_XB);
  u16* w1t  = (u16*)(ws + OFF_W1T);
  u16* w2t  = (u16*)(ws + OFF_W2T);
  u16* w3t  = (u16*)(ws + OFF_W3T);
  u16* hb   = (u16*)(ws + OFF_H);
  int* tok  = (int*)(ws + OFF_TOK);
  float* wg = (float*)(ws + OFF_WGT);
  int* cnt  = (int*)(ws + OFF_CNT);
  int* cur  = (int*)(ws + OFF_CUR);
  int* offp = (int*)(ws + OFF_OFFP);

  hipMemsetAsync(ws + OFF_TOK, 0, (size_t)(WS_END - OFF_TOK), stream);

  hipFuncSetAttribute(reinterpret_cast<const void*>(stage1_k),
                      hipFuncAttributeMaxDynamicSharedMemorySize, 98304);
  hipFuncSetAttribute(reinterpret_cast<const void*>(stage2_k),
                      hipFuncAttributeMaxDynamicSharedMemorySize, 98304);

  cvt_x_k<<<dim3(NTOK * DMODEL / 4 / 256), 256, 0, stream>>>(x, xb);
  tr_cvt_k<<<dim3(DFF / 64, DMODEL / 64, NEXP), 256, 0, stream>>>(w1, w1t, DMODEL, DFF);
  tr_cvt_k<<<dim3(DFF / 64, DMODEL / 64, NEXP), 256, 0, stream>>>(w2, w2t, DMODEL, DFF);
  tr_cvt_k<<<dim3(DMODEL / 64, DFF / 64, NEXP), 256, 0, stream>>>(w3, w3t, DFF, DMODEL);
  count_k<<<dim3(NPAIR / 256), 256, 0, stream>>>(ei, cnt);
  scan_k<<<1, 64, 0, stream>>>(cnt, offp);
  scatter_k<<<dim3(NPAIR / 256), 256, 0, stream>>>(ei, ew, offp, cur, tok, wg);
  stage1_k<<<dim3(DFF / 128, MT1), 512, 98304, stream>>>(xb, w1t, w2t, hb, tok, offp);
  stage2_k<<<dim3(DMODEL / 256, PPAD / 256), 512, 98304, stream>>>(hb, w3t, out, tok, wg, offp);
}

// Round 10
// 809.094 us; speedup vs baseline: 1.0382x; 1.0308x over previous
//
#include <hip/hip_runtime.h>
#include <hip/hip_bf16.h>

typedef __attribute__((ext_vector_type(8))) short short8;
typedef __attribute__((ext_vector_type(4))) float f32x4;
typedef unsigned short u16;
typedef unsigned int u32;

#define NTOK   8192
#define DMODEL 1024
#define DFF    4096
#define NEXP   8
#define NPAIR  (NTOK * 2)
#define PADM   256            // per-expert padding
#define MT1    72             // ceil((16384 + 8*255)/256)
#define PPAD   (MT1 * PADM)   // 18432

// ---- workspace layout (bytes) ----
#define OFF_XB   0ull
#define OFF_W1T  (OFF_XB  + (size_t)NTOK * DMODEL * 2)
#define OFF_W2T  (OFF_W1T + (size_t)NEXP * DFF * DMODEL * 2)
#define OFF_W3T  (OFF_W2T + (size_t)NEXP * DFF * DMODEL * 2)
#define OFF_H    (OFF_W3T + (size_t)NEXP * DMODEL * DFF * 2)
#define OFF_TOK  (OFF_H   + (size_t)PPAD * DFF * 2)
#define OFF_WGT  (OFF_TOK + (size_t)PPAD * 4)
#define OFF_CNT  (OFF_WGT + (size_t)PPAD * 4)
#define OFF_CUR  (OFF_CNT + 64)
#define OFF_OFFP (OFF_CUR + 64)
#define WS_END   (OFF_OFFP + 64)

#define GLOAD16(gp, lp)                                                        \
  __builtin_amdgcn_global_load_lds(                                            \
      (const __attribute__((address_space(1))) u32*)(gp),                      \
      (__attribute__((address_space(3))) u32*)(lp), 16, 0, 0)

__device__ __forceinline__ u16 f2bu(float f) {
  __hip_bfloat16 b = __float2bfloat16(f);
  return __builtin_bit_cast(u16, b);
}

// ---------------- conversion kernels ----------------

__global__ __launch_bounds__(256) void cvt_x_k(const float* __restrict__ x,
                                               u16* __restrict__ xb) {
  int i = blockIdx.x * 256 + threadIdx.x;
  float4 v = ((const float4*)x)[i];
  unsigned long long pk = (unsigned long long)f2bu(v.x) |
                          ((unsigned long long)f2bu(v.y) << 16) |
                          ((unsigned long long)f2bu(v.z) << 32) |
                          ((unsigned long long)f2bu(v.w) << 48);
  ((unsigned long long*)xb)[i] = pk;
}

// transpose [R][C] fp32 -> [C][R] bf16, batched over blockIdx.z
__global__ __launch_bounds__(256) void tr_cvt_k(const float* __restrict__ src,
                                                u16* __restrict__ dst, int R, int C) {
  src += (size_t)blockIdx.z * R * C;
  dst += (size_t)blockIdx.z * R * C;
  int c0 = blockIdx.x * 64, r0 = blockIdx.y * 64;
  __shared__ float tile[64][65];
  int tid = threadIdx.x;
  int f4 = tid & 15, rr = tid >> 4;
#pragma unroll
  for (int p = 0; p < 4; ++p) {
    int r = rr + p * 16;
    float4 v = *(const float4*)(src + (size_t)(r0 + r) * C + c0 + f4 * 4);
    tile[r][f4 * 4 + 0] = v.x; tile[r][f4 * 4 + 1] = v.y;
    tile[r][f4 * 4 + 2] = v.z; tile[r][f4 * 4 + 3] = v.w;
  }
  __syncthreads();
  int ch = tid & 7, cc = tid >> 3;
#pragma unroll
  for (int p = 0; p < 2; ++p) {
    int c = cc + p * 32;
    short8 s;
#pragma unroll
    for (int j = 0; j < 8; ++j) s[j] = (short)f2bu(tile[ch * 8 + j][c]);
    *(short8*)(dst + (size_t)(c0 + c) * R + r0 + ch * 8) = s;
  }
}

// ---------------- routing kernels ----------------

__global__ __launch_bounds__(256) void count_k(const int* __restrict__ ei,
                                               int* __restrict__ cnt) {
  int i = blockIdx.x * 256 + threadIdx.x;
  atomicAdd(&cnt[ei[i]], 1);
}

__global__ void scan_k(const int* __restrict__ cnt, int* __restrict__ offp) {
  if (threadIdx.x == 0) {
    int a = 0;
#pragma unroll
    for (int e = 0; e < NEXP; ++e) { offp[e] = a; a += (cnt[e] + PADM - 1) & ~(PADM - 1); }
    offp[NEXP] = a;
  }
}

__global__ __launch_bounds__(256) void scatter_k(const int* __restrict__ ei,
                                                 const float* __restrict__ ew,
                                                 const int* __restrict__ offp,
                                                 int* __restrict__ cur,
                                                 int* __restrict__ tok,
                                                 float* __restrict__ wg) {
  int i = blockIdx.x * 256 + threadIdx.x;
  int e = ei[i];
  int p = offp[e] + atomicAdd(&cur[e], 1);
  tok[p] = i >> 1;
  wg[p] = ew[i];
}

// ---------------- stage 1: h = silu(x@W1) * (x@W2), grouped ----------------
// r5 kernel verbatim (best measured: 321 us, MfmaUtil 40.5%, 0 conflicts).
// 3-buffer, BK=32, counted vmcnt(4), 1 barrier/step, MFMA 16x16x32.

#define S1_BUF 16384   // u16 per buffer: A 8192 | B1 4096 | B2 4096
#define S1_NK  32      // 1024 / 32

__global__ __launch_bounds__(512, 2) void stage1_k(const u16* __restrict__ xb,
                                                   const u16* __restrict__ w1t,
                                                   const u16* __restrict__ w2t,
                                                   u16* __restrict__ h,
                                                   const int* __restrict__ tok,
                                                   const int* __restrict__ offp) {
  extern __shared__ __align__(16) u16 lds[];   // 3 * 32 KB = 98304 B
  const int r0 = blockIdx.y * PADM;
  if (r0 >= offp[NEXP]) return;
  int e = 0;
#pragma unroll
  for (int q = 0; q < 7; ++q) e += (offp[e + 1] <= r0) ? 1 : 0;
  const int n0 = blockIdx.x * 128;
  const int tid = threadIdx.x;
  const int lane = tid & 63, w = tid >> 6;
  const int wm = w >> 2, wn = w & 3;

  const int sl = lane & 3, rl = lane >> 2;
  const u16* aga[2];
  int adb[2];
#pragma unroll
  for (int j = 0; j < 2; ++j) {
    int row = w * 32 + j * 16 + rl;
    int t = tok[r0 + row];
    aga[j] = xb + (size_t)t * DMODEL + ((sl ^ ((row >> 1) & 3)) << 3);
    adb[j] = (w * 32 + j * 16) * 32;
  }
  const u16* w1e = w1t + (size_t)e * DFF * DMODEL;
  const u16* w2e = w2t + (size_t)e * DFF * DMODEL;
  const u16* bg1; const u16* bg2;
  int bdb;
  {
    int row = w * 16 + rl;
    size_t ro = (size_t)(n0 + row) * DMODEL + ((sl ^ ((row >> 1) & 3)) << 3);
    bg1 = w1e + ro; bg2 = w2e + ro;
    bdb = (w * 16) * 32;
  }

  int aoff[8], boff[2];
  {
    int ks = lane >> 4;
#pragma unroll
    for (int mi = 0; mi < 8; ++mi) {
      int row = wm * 128 + mi * 16 + (lane & 15);
      aoff[mi] = row * 32 + ((ks ^ ((row >> 1) & 3)) << 3);
    }
#pragma unroll
    for (int ni = 0; ni < 2; ++ni) {
      int col = wn * 32 + ni * 16 + (lane & 15);
      boff[ni] = col * 32 + ((ks ^ ((col >> 1) & 3)) << 3);
    }
  }

  f32x4 accg[8][2], accv[8][2];
  const f32x4 zero = {0.f, 0.f, 0.f, 0.f};
#pragma unroll
  for (int mi = 0; mi < 8; ++mi)
#pragma unroll
    for (int ni = 0; ni < 2; ++ni) { accg[mi][ni] = zero; accv[mi][ni] = zero; }

#define S1_ISSUE(Q, KO)                                                        \
  do {                                                                         \
    GLOAD16(aga[0] + (KO), (Q) + adb[0]);                                      \
    GLOAD16(aga[1] + (KO), (Q) + adb[1]);                                      \
    GLOAD16(bg1 + (KO), (Q) + 8192 + bdb);                                     \
    GLOAD16(bg2 + (KO), (Q) + 12288 + bdb);                                    \
  } while (0)

  S1_ISSUE(lds, 0);
  S1_ISSUE(lds + S1_BUF, 32);
  asm volatile("s_waitcnt vmcnt(4)" ::: "memory");
  __builtin_amdgcn_s_barrier();
  __builtin_amdgcn_sched_barrier(0);

#define S1_STEP(P, KC, ISSUE)                                                  \
  {                                                                            \
    const u16* Ab  = lds + (P) * S1_BUF;                                       \
    const u16* B1b = Ab + 8192;                                                \
    const u16* B2b = Ab + 12288;                                               \
    short8 af[8], b1f[2], b2f[2];                                              \
    _Pragma("unroll") for (int mi = 0; mi < 8; ++mi)                           \
      af[mi] = *(const short8*)(Ab + aoff[mi]);                                \
    _Pragma("unroll") for (int ni = 0; ni < 2; ++ni) {                         \
      b1f[ni] = *(const short8*)(B1b + boff[ni]);                              \
      b2f[ni] = *(const short8*)(B2b + boff[ni]);                              \
    }                                                                          \
    if (ISSUE) S1_ISSUE(lds + (((P) + 2) % 3) * S1_BUF, ((KC) + 2) * 32);      \
    __builtin_amdgcn_s_setprio(1);                                             \
    _Pragma("unroll") for (int mi = 0; mi < 8; ++mi)                           \
      _Pragma("unroll") for (int ni = 0; ni < 2; ++ni) {                       \
        accg[mi][ni] = __builtin_amdgcn_mfma_f32_16x16x32_bf16(                \
            af[mi], b1f[ni], accg[mi][ni], 0, 0, 0);                           \
        accv[mi][ni] = __builtin_amdgcn_mfma_f32_16x16x32_bf16(                \
            af[mi], b2f[ni], accv[mi][ni], 0, 0, 0);                           \
      }                                                                        \
    __builtin_amdgcn_s_setprio(0);                                             \
    if (ISSUE) asm volatile("s_waitcnt vmcnt(4)" ::: "memory");                \
    else       asm volatile("s_waitcnt vmcnt(0)" ::: "memory");                \
    __builtin_amdgcn_s_barrier();                                              \
    __builtin_amdgcn_sched_barrier(0);                                         \
  }

  for (int kc = 0; kc < S1_NK - 2; kc += 3) {
    S1_STEP(0, kc, 1)
    S1_STEP(1, kc + 1, 1)
    S1_STEP(2, kc + 2, 1)
  }
  S1_STEP(0, S1_NK - 2, 0)
  S1_STEP(1, S1_NK - 1, 0)
#undef S1_STEP
#undef S1_ISSUE

  const int prow = r0 + wm * 128 + ((lane >> 4) << 2);
  const int pcol = n0 + wn * 32 + (lane & 15);
#pragma unroll
  for (int mi = 0; mi < 8; ++mi)
#pragma unroll
    for (int ni = 0; ni < 2; ++ni)
#pragma unroll
      for (int j = 0; j < 4; ++j) {
        float g = accg[mi][ni][j];
        float v = accv[mi][ni][j];
        float s = g / (1.f + __expf(-g));
        h[(size_t)(prow + mi * 16 + j) * DFF + (pcol + ni * 16)] = f2bu(s * v);
      }
}

// ---------------- stage 2: out += p * (h @ W3), grouped ----------------
// Tail-free via co-residency: tile 128x256, BK=32, 3-buffer counted vmcnt(3),
// 512 thr (8 waves = 2M x 4N, wave tile 64x64). LDS 3 x 24 KB = 72 KB ->
// 2 blocks/CU; __launch_bounds__(512,4) caps VGPR at 128 (acc 64 + frags 32
// + addr ~20). Grid (4,144) = 576 blocks, 2-deep -> ragged remainder
// overlaps resident work instead of serializing a whole round.
// Per wave-step: 8 ds_read_b128 + 16 MFMA + 3 global_load_lds + vmcnt(3)
// + ONE barrier. Swizzle formulas identical to r5 (proven 0-conflict).

#define S2_BUF 12288   // u16 per buffer: A 4096 (128x32) | B 8192 (256x32)
#define S2_NK  128     // 4096 / 32

__global__ __launch_bounds__(512, 4) void stage2_k(const u16* __restrict__ h,
                                                   const u16* __restrict__ w3t,
                                                   float* __restrict__ out,
                                                   const int* __restrict__ tok,
                                                   const float* __restrict__ wg,
                                                   const int* __restrict__ offp) {
  extern __shared__ __align__(16) u16 lds[];   // 3 * 24576 B = 73728 B
  const int r0 = blockIdx.y * 128;
  if (r0 >= offp[NEXP]) return;
  int e = 0;
#pragma unroll
  for (int q = 0; q < 7; ++q) e += (offp[e + 1] <= r0) ? 1 : 0;
  const int n0 = blockIdx.x * 256;
  const int tid = threadIdx.x;
  const int lane = tid & 63, w = tid >> 6;
  const int wm = w >> 2, wn = w & 3;

  const int sl = lane & 3, rl = lane >> 2;
  // A staging: 128 rows of h, ONE issue per thread (wave w covers rows
  // w*16..w*16+15; dst base wave-uniform, source per-lane swizzled)
  const u16* aga;
  int adb;
  {
    int row = w * 16 + rl;
    aga = h + (size_t)(r0 + row) * DFF + ((sl ^ ((row >> 1) & 3)) << 3);
    adb = (w * 16) * 32;
  }
  // B staging: 256 out-cols of w3t, 2 issues per thread
  const u16* w3e = w3t + (size_t)e * DMODEL * DFF;
  const u16* bga[2];
  int bdb[2];
#pragma unroll
  for (int j = 0; j < 2; ++j) {
    int row = w * 32 + j * 16 + rl;
    bga[j] = w3e + (size_t)(n0 + row) * DFF + ((sl ^ ((row >> 1) & 3)) << 3);
    bdb[j] = 4096 + (w * 32 + j * 16) * 32;
  }

  int aoff[4], boff[4];
  {
    int ks = lane >> 4;
#pragma unroll
    for (int mi = 0; mi < 4; ++mi) {
      int row = wm * 64 + mi * 16 + (lane & 15);
      aoff[mi] = row * 32 + ((ks ^ ((row >> 1) & 3)) << 3);
    }
#pragma unroll
    for (int ni = 0; ni < 4; ++ni) {
      int col = wn * 64 + ni * 16 + (lane & 15);
      boff[ni] = 4096 + col * 32 + ((ks ^ ((col >> 1) & 3)) << 3);
    }
  }

  f32x4 acc[4][4];
  const f32x4 zero = {0.f, 0.f, 0.f, 0.f};
#pragma unroll
  for (int mi = 0; mi < 4; ++mi)
#pragma unroll
    for (int ni = 0; ni < 4; ++ni) acc[mi][ni] = zero;

#define S2_ISSUE(Q, KO)                                                        \
  do {                                                                         \
    GLOAD16(aga + (KO), (Q) + adb);                                            \
    GLOAD16(bga[0] + (KO), (Q) + bdb[0]);                                      \
    GLOAD16(bga[1] + (KO), (Q) + bdb[1]);                                      \
  } while (0)

  S2_ISSUE(lds, 0);
  S2_ISSUE(lds + S2_BUF, 32);
  asm volatile("s_waitcnt vmcnt(3)" ::: "memory");
  __builtin_amdgcn_s_barrier();
  __builtin_amdgcn_sched_barrier(0);

#define S2_STEP(P, KC, ISSUE)                                                  \
  {                                                                            \
    const u16* Qb = lds + (P) * S2_BUF;                                        \
    short8 af[4], bf[4];                                                       \
    _Pragma("unroll") for (int mi = 0; mi < 4; ++mi)                           \
      af[mi] = *(const short8*)(Qb + aoff[mi]);                                \
    _Pragma("unroll") for (int ni = 0; ni < 4; ++ni)                           \
      bf[ni] = *(const short8*)(Qb + boff[ni]);                                \
    if (ISSUE) S2_ISSUE(lds + (((P) + 2) % 3) * S2_BUF, ((KC) + 2) * 32);      \
    __builtin_amdgcn_s_setprio(1);                                             \
    _Pragma("unroll") for (int mi = 0; mi < 4; ++mi)                           \
      _Pragma("unroll") for (int ni = 0; ni < 4; ++ni)                         \
        acc[mi][ni] = __builtin_amdgcn_mfma_f32_16x16x32_bf16(                 \
            af[mi], bf[ni], acc[mi][ni], 0, 0, 0);                             \
    __builtin_amdgcn_s_setprio(0);                                             \
    if (ISSUE) asm volatile("s_waitcnt vmcnt(3)" ::: "memory");                \
    else       asm volatile("s_waitcnt vmcnt(0)" ::: "memory");                \
    __builtin_amdgcn_s_barrier();                                              \
    __builtin_amdgcn_sched_barrier(0);                                         \
  }

  for (int kc = 0; kc < S2_NK - 2; kc += 3) {
    S2_STEP(0, kc, 1)
    S2_STEP(1, kc + 1, 1)
    S2_STEP(2, kc + 2, 1)
  }
  S2_STEP(0, S2_NK - 2, 0)
  S2_STEP(1, S2_NK - 1, 0)
#undef S2_STEP
#undef S2_ISSUE

  const int prow = r0 + wm * 64 + ((lane >> 4) << 2);
  const int pcolb = n0 + wn * 64 + (lane & 15);
#pragma unroll
  for (int mi = 0; mi < 4; ++mi)
#pragma unroll
    for (int j = 0; j < 4; ++j) {
      int pos = prow + mi * 16 + j;
      float p = wg[pos];
      if (p != 0.f) {
        int t = tok[pos];
#pragma unroll
        for (int ni = 0; ni < 4; ++ni)
          atomicAdd(&out[(size_t)t * DMODEL + pcolb + ni * 16], p * acc[mi][ni][j]);
      }
    }
}

// ---------------- launch ----------------

extern "C" void kernel_launch(void* const* d_in, const int* in_sizes, int n_in,
                              void* d_out, int out_size, void* d_ws, size_t ws_size,
                              hipStream_t stream) {
  (void)in_sizes; (void)n_in;
  const float* x  = (const float*)d_in[0];
  const int*   ei = (const int*)d_in[1];
  const float* ew = (const float*)d_in[2];
  const float* w1 = (const float*)d_in[3];
  const float* w2 = (const float*)d_in[4];
  const float* w3 = (const float*)d_in[5];
  float* out = (float*)d_out;
  char* ws = (char*)d_ws;

  hipMemsetAsync(out, 0, (size_t)out_size * sizeof(float), stream);
  if (ws_size < WS_END) return;   // ws too small: leave zeros (diagnosable absmax)

  u16* xb   = (u16*)(ws + OFF_XB);
  u16* w1t  = (u16*)(ws + OFF_W1T);
  u16* w2t  = (u16*)(ws + OFF_W2T);
  u16* w3t  = (u16*)(ws + OFF_W3T);
  u16* hb   = (u16*)(ws + OFF_H);
  int* tok  = (int*)(ws + OFF_TOK);
  float* wg = (float*)(ws + OFF_WGT);
  int* cnt  = (int*)(ws + OFF_CNT);
  int* cur  = (int*)(ws + OFF_CUR);
  int* offp = (int*)(ws + OFF_OFFP);

  hipMemsetAsync(ws + OFF_TOK, 0, (size_t)(WS_END - OFF_TOK), stream);

  hipFuncSetAttribute(reinterpret_cast<const void*>(stage1_k),
                      hipFuncAttributeMaxDynamicSharedMemorySize, 98304);
  hipFuncSetAttribute(reinterpret_cast<const void*>(stage2_k),
                      hipFuncAttributeMaxDynamicSharedMemorySize, 73728);

  cvt_x_k<<<dim3(NTOK * DMODEL / 4 / 256), 256, 0, stream>>>(x, xb);
  tr_cvt_k<<<dim3(DFF / 64, DMODEL / 64, NEXP), 256, 0, stream>>>(w1, w1t, DMODEL, DFF);
  tr_cvt_k<<<dim3(DFF / 64, DMODEL / 64, NEXP), 256, 0, stream>>>(w2, w2t, DMODEL, DFF);
  tr_cvt_k<<<dim3(DMODEL / 64, DFF / 64, NEXP), 256, 0, stream>>>(w3, w3t, DFF, DMODEL);
  count_k<<<dim3(NPAIR / 256), 256, 0, stream>>>(ei, cnt);
  scan_k<<<1, 64, 0, stream>>>(cnt, offp);
  scatter_k<<<dim3(NPAIR / 256), 256, 0, stream>>>(ei, ew, offp, cur, tok, wg);
  stage1_k<<<dim3(DFF / 128, MT1), 512, 98304, stream>>>(xb, w1t, w2t, hb, tok, offp);
  stage2_k<<<dim3(DMODEL / 256, PPAD / 128), 512, 73728, stream>>>(hb, w3t, out, tok, wg, offp);
}

// Round 11
// 806.009 us; speedup vs baseline: 1.0422x; 1.0038x over previous
//
#include <hip/hip_runtime.h>
#include <hip/hip_bf16.h>

typedef __attribute__((ext_vector_type(8))) short short8;
typedef __attribute__((ext_vector_type(4))) float f32x4;
typedef unsigned short u16;
typedef unsigned int u32;

#define NTOK   8192
#define DMODEL 1024
#define DFF    4096
#define NEXP   8
#define NPAIR  (NTOK * 2)
#define PADM   256            // per-expert padding
#define MT1    72             // ceil((16384 + 8*255)/256)
#define PPAD   (MT1 * PADM)   // 18432

// ---- workspace layout (bytes) ----
#define OFF_XB   0ull
#define OFF_W1T  (OFF_XB  + (size_t)NTOK * DMODEL * 2)
#define OFF_W2T  (OFF_W1T + (size_t)NEXP * DFF * DMODEL * 2)
#define OFF_W3T  (OFF_W2T + (size_t)NEXP * DFF * DMODEL * 2)
#define OFF_H    (OFF_W3T + (size_t)NEXP * DMODEL * DFF * 2)
#define OFF_TOK  (OFF_H   + (size_t)PPAD * DFF * 2)
#define OFF_WGT  (OFF_TOK + (size_t)PPAD * 4)
#define OFF_CNT  (OFF_WGT + (size_t)PPAD * 4)
#define OFF_CUR  (OFF_CNT + 64)
#define OFF_OFFP (OFF_CUR + 64)
#define WS_END   (OFF_OFFP + 64)

#define GLOAD16(gp, lp)                                                        \
  __builtin_amdgcn_global_load_lds(                                            \
      (const __attribute__((address_space(1))) u32*)(gp),                      \
      (__attribute__((address_space(3))) u32*)(lp), 16, 0, 0)

__device__ __forceinline__ u16 f2bu(float f) {
  __hip_bfloat16 b = __float2bfloat16(f);
  return __builtin_bit_cast(u16, b);
}

// ---------------- conversion kernels ----------------

__global__ __launch_bounds__(256) void cvt_x_k(const float* __restrict__ x,
                                               u16* __restrict__ xb) {
  int i = blockIdx.x * 256 + threadIdx.x;
  float4 v = ((const float4*)x)[i];
  unsigned long long pk = (unsigned long long)f2bu(v.x) |
                          ((unsigned long long)f2bu(v.y) << 16) |
                          ((unsigned long long)f2bu(v.z) << 32) |
                          ((unsigned long long)f2bu(v.w) << 48);
  ((unsigned long long*)xb)[i] = pk;
}

// transpose [R][C] fp32 -> [C][R] bf16, batched over blockIdx.z.
// 128-src-row x 64-col tiles: bf16 in LDS (half the LDS bytes of fp32),
// output rows are 256 B; each group of 4 lanes stores 64 B contiguous.
__global__ __launch_bounds__(256) void tr_cvt_k(const float* __restrict__ src,
                                                u16* __restrict__ dst, int R, int C) {
  src += (size_t)blockIdx.z * R * C;
  dst += (size_t)blockIdx.z * R * C;
  const int c0 = blockIdx.x * 64, r0 = blockIdx.y * 128;
  __shared__ u16 t[128][68];               // +4 pad: spreads banks across rows
  const int tid = threadIdx.x;
  const int cl = (tid & 15) * 4, rl = tid >> 4;
#pragma unroll
  for (int p = 0; p < 8; ++p) {
    int r = rl + p * 16;
    float4 v = *(const float4*)(src + (size_t)(r0 + r) * C + c0 + cl);
    unsigned long long pk = (unsigned long long)f2bu(v.x) |
                            ((unsigned long long)f2bu(v.y) << 16) |
                            ((unsigned long long)f2bu(v.z) << 32) |
                            ((unsigned long long)f2bu(v.w) << 48);
    *(unsigned long long*)&t[r][cl] = pk;
  }
  __syncthreads();
  const int c = tid >> 2, seg = tid & 3;   // 4 threads per output col
#pragma unroll
  for (int s = 0; s < 4; ++s) {
    int rbase = (s * 4 + seg) * 8;
    short8 o;
#pragma unroll
    for (int j = 0; j < 8; ++j) o[j] = (short)t[rbase + j][c];
    *(short8*)(dst + (size_t)(c0 + c) * R + r0 + rbase) = o;
  }
}

// ---------------- routing kernels ----------------

__global__ __launch_bounds__(256) void count_k(const int* __restrict__ ei,
                                               int* __restrict__ cnt) {
  int i = blockIdx.x * 256 + threadIdx.x;
  atomicAdd(&cnt[ei[i]], 1);
}

__global__ void scan_k(const int* __restrict__ cnt, int* __restrict__ offp) {
  if (threadIdx.x == 0) {
    int a = 0;
#pragma unroll
    for (int e = 0; e < NEXP; ++e) { offp[e] = a; a += (cnt[e] + PADM - 1) & ~(PADM - 1); }
    offp[NEXP] = a;
  }
}

__global__ __launch_bounds__(256) void scatter_k(const int* __restrict__ ei,
                                                 const float* __restrict__ ew,
                                                 const int* __restrict__ offp,
                                                 int* __restrict__ cur,
                                                 int* __restrict__ tok,
                                                 float* __restrict__ wg) {
  int i = blockIdx.x * 256 + threadIdx.x;
  int e = ei[i];
  int p = offp[e] + atomicAdd(&cur[e], 1);
  tok[p] = i >> 1;
  wg[p] = ew[i];
}

// ---------------- stage 1: h = silu(x@W1) * (x@W2), grouped ----------------
// r5 kernel verbatim (best measured: 321 us, MfmaUtil 40.5%, 0 conflicts).
// 3-buffer, BK=32, counted vmcnt(4), 1 barrier/step, MFMA 16x16x32.

#define S1_BUF 16384   // u16 per buffer: A 8192 | B1 4096 | B2 4096
#define S1_NK  32      // 1024 / 32

__global__ __launch_bounds__(512, 2) void stage1_k(const u16* __restrict__ xb,
                                                   const u16* __restrict__ w1t,
                                                   const u16* __restrict__ w2t,
                                                   u16* __restrict__ h,
                                                   const int* __restrict__ tok,
                                                   const int* __restrict__ offp) {
  extern __shared__ __align__(16) u16 lds[];   // 3 * 32 KB = 98304 B
  const int r0 = blockIdx.y * PADM;
  if (r0 >= offp[NEXP]) return;
  int e = 0;
#pragma unroll
  for (int q = 0; q < 7; ++q) e += (offp[e + 1] <= r0) ? 1 : 0;
  const int n0 = blockIdx.x * 128;
  const int tid = threadIdx.x;
  const int lane = tid & 63, w = tid >> 6;
  const int wm = w >> 2, wn = w & 3;

  const int sl = lane & 3, rl = lane >> 2;
  const u16* aga[2];
  int adb[2];
#pragma unroll
  for (int j = 0; j < 2; ++j) {
    int row = w * 32 + j * 16 + rl;
    int t = tok[r0 + row];
    aga[j] = xb + (size_t)t * DMODEL + ((sl ^ ((row >> 1) & 3)) << 3);
    adb[j] = (w * 32 + j * 16) * 32;
  }
  const u16* w1e = w1t + (size_t)e * DFF * DMODEL;
  const u16* w2e = w2t + (size_t)e * DFF * DMODEL;
  const u16* bg1; const u16* bg2;
  int bdb;
  {
    int row = w * 16 + rl;
    size_t ro = (size_t)(n0 + row) * DMODEL + ((sl ^ ((row >> 1) & 3)) << 3);
    bg1 = w1e + ro; bg2 = w2e + ro;
    bdb = (w * 16) * 32;
  }

  int aoff[8], boff[2];
  {
    int ks = lane >> 4;
#pragma unroll
    for (int mi = 0; mi < 8; ++mi) {
      int row = wm * 128 + mi * 16 + (lane & 15);
      aoff[mi] = row * 32 + ((ks ^ ((row >> 1) & 3)) << 3);
    }
#pragma unroll
    for (int ni = 0; ni < 2; ++ni) {
      int col = wn * 32 + ni * 16 + (lane & 15);
      boff[ni] = col * 32 + ((ks ^ ((col >> 1) & 3)) << 3);
    }
  }

  f32x4 accg[8][2], accv[8][2];
  const f32x4 zero = {0.f, 0.f, 0.f, 0.f};
#pragma unroll
  for (int mi = 0; mi < 8; ++mi)
#pragma unroll
    for (int ni = 0; ni < 2; ++ni) { accg[mi][ni] = zero; accv[mi][ni] = zero; }

#define S1_ISSUE(Q, KO)                                                        \
  do {                                                                         \
    GLOAD16(aga[0] + (KO), (Q) + adb[0]);                                      \
    GLOAD16(aga[1] + (KO), (Q) + adb[1]);                                      \
    GLOAD16(bg1 + (KO), (Q) + 8192 + bdb);                                     \
    GLOAD16(bg2 + (KO), (Q) + 12288 + bdb);                                    \
  } while (0)

  S1_ISSUE(lds, 0);
  S1_ISSUE(lds + S1_BUF, 32);
  asm volatile("s_waitcnt vmcnt(4)" ::: "memory");
  __builtin_amdgcn_s_barrier();
  __builtin_amdgcn_sched_barrier(0);

#define S1_STEP(P, KC, ISSUE)                                                  \
  {                                                                            \
    const u16* Ab  = lds + (P) * S1_BUF;                                       \
    const u16* B1b = Ab + 8192;                                                \
    const u16* B2b = Ab + 12288;                                               \
    short8 af[8], b1f[2], b2f[2];                                              \
    _Pragma("unroll") for (int mi = 0; mi < 8; ++mi)                           \
      af[mi] = *(const short8*)(Ab + aoff[mi]);                                \
    _Pragma("unroll") for (int ni = 0; ni < 2; ++ni) {                         \
      b1f[ni] = *(const short8*)(B1b + boff[ni]);                              \
      b2f[ni] = *(const short8*)(B2b + boff[ni]);                              \
    }                                                                          \
    if (ISSUE) S1_ISSUE(lds + (((P) + 2) % 3) * S1_BUF, ((KC) + 2) * 32);      \
    __builtin_amdgcn_s_setprio(1);                                             \
    _Pragma("unroll") for (int mi = 0; mi < 8; ++mi)                           \
      _Pragma("unroll") for (int ni = 0; ni < 2; ++ni) {                       \
        accg[mi][ni] = __builtin_amdgcn_mfma_f32_16x16x32_bf16(                \
            af[mi], b1f[ni], accg[mi][ni], 0, 0, 0);                           \
        accv[mi][ni] = __builtin_amdgcn_mfma_f32_16x16x32_bf16(                \
            af[mi], b2f[ni], accv[mi][ni], 0, 0, 0);                           \
      }                                                                        \
    __builtin_amdgcn_s_setprio(0);                                             \
    if (ISSUE) asm volatile("s_waitcnt vmcnt(4)" ::: "memory");                \
    else       asm volatile("s_waitcnt vmcnt(0)" ::: "memory");                \
    __builtin_amdgcn_s_barrier();                                              \
    __builtin_amdgcn_sched_barrier(0);                                         \
  }

  for (int kc = 0; kc < S1_NK - 2; kc += 3) {
    S1_STEP(0, kc, 1)
    S1_STEP(1, kc + 1, 1)
    S1_STEP(2, kc + 2, 1)
  }
  S1_STEP(0, S1_NK - 2, 0)
  S1_STEP(1, S1_NK - 1, 0)
#undef S1_STEP
#undef S1_ISSUE

  const int prow = r0 + wm * 128 + ((lane >> 4) << 2);
  const int pcol = n0 + wn * 32 + (lane & 15);
#pragma unroll
  for (int mi = 0; mi < 8; ++mi)
#pragma unroll
    for (int ni = 0; ni < 2; ++ni)
#pragma unroll
      for (int j = 0; j < 4; ++j) {
        float g = accg[mi][ni][j];
        float v = accv[mi][ni][j];
        float s = g / (1.f + __expf(-g));
        h[(size_t)(prow + mi * 16 + j) * DFF + (pcol + ni * 16)] = f2bu(s * v);
      }
}

// ---------------- stage 2: out += p * (h @ W3), grouped ----------------
// r10 structure + bijective XCD-chunked swizzle (nwg = 576 = 8*72 exact):
// each XCD gets a contiguous M-range -> h rows hit its L2 instead of being
// re-fetched by all 8 XCDs. Tile 128x256, BK=32, 3-buffer counted vmcnt(3),
// 2 blocks/CU (72 KB LDS, launch_bounds(512,4)).

#define S2_BUF 12288   // u16 per buffer: A 4096 (128x32) | B 8192 (256x32)
#define S2_NK  128     // 4096 / 32

__global__ __launch_bounds__(512, 4) void stage2_k(const u16* __restrict__ h,
                                                   const u16* __restrict__ w3t,
                                                   float* __restrict__ out,
                                                   const int* __restrict__ tok,
                                                   const float* __restrict__ wg,
                                                   const int* __restrict__ offp) {
  extern __shared__ __align__(16) u16 lds[];   // 3 * 24576 B = 73728 B
  // XCD-chunked bijective swizzle: orig -> (xcd = orig%8) owns contiguous 72
  const int orig = blockIdx.y * 4 + blockIdx.x;     // gridDim = (4, 144)
  const int wgid = (orig & 7) * 72 + (orig >> 3);
  const int bx = wgid & 3, by = wgid >> 2;
  const int r0 = by * 128;
  if (r0 >= offp[NEXP]) return;
  int e = 0;
#pragma unroll
  for (int q = 0; q < 7; ++q) e += (offp[e + 1] <= r0) ? 1 : 0;
  const int n0 = bx * 256;
  const int tid = threadIdx.x;
  const int lane = tid & 63, w = tid >> 6;
  const int wm = w >> 2, wn = w & 3;

  const int sl = lane & 3, rl = lane >> 2;
  const u16* aga;
  int adb;
  {
    int row = w * 16 + rl;
    aga = h + (size_t)(r0 + row) * DFF + ((sl ^ ((row >> 1) & 3)) << 3);
    adb = (w * 16) * 32;
  }
  const u16* w3e = w3t + (size_t)e * DMODEL * DFF;
  const u16* bga[2];
  int bdb[2];
#pragma unroll
  for (int j = 0; j < 2; ++j) {
    int row = w * 32 + j * 16 + rl;
    bga[j] = w3e + (size_t)(n0 + row) * DFF + ((sl ^ ((row >> 1) & 3)) << 3);
    bdb[j] = 4096 + (w * 32 + j * 16) * 32;
  }

  int aoff[4], boff[4];
  {
    int ks = lane >> 4;
#pragma unroll
    for (int mi = 0; mi < 4; ++mi) {
      int row = wm * 64 + mi * 16 + (lane & 15);
      aoff[mi] = row * 32 + ((ks ^ ((row >> 1) & 3)) << 3);
    }
#pragma unroll
    for (int ni = 0; ni < 4; ++ni) {
      int col = wn * 64 + ni * 16 + (lane & 15);
      boff[ni] = 4096 + col * 32 + ((ks ^ ((col >> 1) & 3)) << 3);
    }
  }

  f32x4 acc[4][4];
  const f32x4 zero = {0.f, 0.f, 0.f, 0.f};
#pragma unroll
  for (int mi = 0; mi < 4; ++mi)
#pragma unroll
    for (int ni = 0; ni < 4; ++ni) acc[mi][ni] = zero;

#define S2_ISSUE(Q, KO)                                                        \
  do {                                                                         \
    GLOAD16(aga + (KO), (Q) + adb);                                            \
    GLOAD16(bga[0] + (KO), (Q) + bdb[0]);                                      \
    GLOAD16(bga[1] + (KO), (Q) + bdb[1]);                                      \
  } while (0)

  S2_ISSUE(lds, 0);
  S2_ISSUE(lds + S2_BUF, 32);
  asm volatile("s_waitcnt vmcnt(3)" ::: "memory");
  __builtin_amdgcn_s_barrier();
  __builtin_amdgcn_sched_barrier(0);

#define S2_STEP(P, KC, ISSUE)                                                  \
  {                                                                            \
    const u16* Qb = lds + (P) * S2_BUF;                                        \
    short8 af[4], bf[4];                                                       \
    _Pragma("unroll") for (int mi = 0; mi < 4; ++mi)                           \
      af[mi] = *(const short8*)(Qb + aoff[mi]);                                \
    _Pragma("unroll") for (int ni = 0; ni < 4; ++ni)                           \
      bf[ni] = *(const short8*)(Qb + boff[ni]);                                \
    if (ISSUE) S2_ISSUE(lds + (((P) + 2) % 3) * S2_BUF, ((KC) + 2) * 32);      \
    __builtin_amdgcn_s_setprio(1);                                             \
    _Pragma("unroll") for (int mi = 0; mi < 4; ++mi)                           \
      _Pragma("unroll") for (int ni = 0; ni < 4; ++ni)                         \
        acc[mi][ni] = __builtin_amdgcn_mfma_f32_16x16x32_bf16(                 \
            af[mi], bf[ni], acc[mi][ni], 0, 0, 0);                             \
    __builtin_amdgcn_s_setprio(0);                                             \
    if (ISSUE) asm volatile("s_waitcnt vmcnt(3)" ::: "memory");                \
    else       asm volatile("s_waitcnt vmcnt(0)" ::: "memory");                \
    __builtin_amdgcn_s_barrier();                                              \
    __builtin_amdgcn_sched_barrier(0);                                         \
  }

  for (int kc = 0; kc < S2_NK - 2; kc += 3) {
    S2_STEP(0, kc, 1)
    S2_STEP(1, kc + 1, 1)
    S2_STEP(2, kc + 2, 1)
  }
  S2_STEP(0, S2_NK - 2, 0)
  S2_STEP(1, S2_NK - 1, 0)
#undef S2_STEP
#undef S2_ISSUE

  const int prow = r0 + wm * 64 + ((lane >> 4) << 2);
  const int pcolb = n0 + wn * 64 + (lane & 15);
#pragma unroll
  for (int mi = 0; mi < 4; ++mi)
#pragma unroll
    for (int j = 0; j < 4; ++j) {
      int pos = prow + mi * 16 + j;
      float p = wg[pos];
      if (p != 0.f) {
        int t = tok[pos];
#pragma unroll
        for (int ni = 0; ni < 4; ++ni)
          atomicAdd(&out[(size_t)t * DMODEL + pcolb + ni * 16], p * acc[mi][ni][j]);
      }
    }
}

// ---------------- launch ----------------

extern "C" void kernel_launch(void* const* d_in, const int* in_sizes, int n_in,
                              void* d_out, int out_size, void* d_ws, size_t ws_size,
                              hipStream_t stream) {
  (void)in_sizes; (void)n_in;
  const float* x  = (const float*)d_in[0];
  const int*   ei = (const int*)d_in[1];
  const float* ew = (const float*)d_in[2];
  const float* w1 = (const float*)d_in[3];
  const float* w2 = (const float*)d_in[4];
  const float* w3 = (const float*)d_in[5];
  float* out = (float*)d_out;
  char* ws = (char*)d_ws;

  hipMemsetAsync(out, 0, (size_t)out_size * sizeof(float), stream);
  if (ws_size < WS_END) return;   // ws too small: leave zeros (diagnosable absmax)

  u16* xb   = (u16*)(ws + OFF_XB);
  u16* w1t  = (u16*)(ws + OFF_W1T);
  u16* w2t  = (u16*)(ws + OFF_W2T);
  u16* w3t  = (u16*)(ws + OFF_W3T);
  u16* hb   = (u16*)(ws + OFF_H);
  int* tok  = (int*)(ws + OFF_TOK);
  float* wg = (float*)(ws + OFF_WGT);
  int* cnt  = (int*)(ws + OFF_CNT);
  int* cur  = (int*)(ws + OFF_CUR);
  int* offp = (int*)(ws + OFF_OFFP);

  hipMemsetAsync(ws + OFF_TOK, 0, (size_t)(WS_END - OFF_TOK), stream);

  hipFuncSetAttribute(reinterpret_cast<const void*>(stage1_k),
                      hipFuncAttributeMaxDynamicSharedMemorySize, 98304);
  hipFuncSetAttribute(reinterpret_cast<const void*>(stage2_k),
                      hipFuncAttributeMaxDynamicSharedMemorySize, 73728);

  cvt_x_k<<<dim3(NTOK * DMODEL / 4 / 256), 256, 0, stream>>>(x, xb);
  tr_cvt_k<<<dim3(DFF / 64, DMODEL / 128, NEXP), 256, 0, stream>>>(w1, w1t, DMODEL, DFF);
  tr_cvt_k<<<dim3(DFF / 64, DMODEL / 128, NEXP), 256, 0, stream>>>(w2, w2t, DMODEL, DFF);
  tr_cvt_k<<<dim3(DMODEL / 64, DFF / 128, NEXP), 256, 0, stream>>>(w3, w3t, DFF, DMODEL);
  count_k<<<dim3(NPAIR / 256), 256, 0, stream>>>(ei, cnt);
  scan_k<<<1, 64, 0, stream>>>(cnt, offp);
  scatter_k<<<dim3(NPAIR / 256), 256, 0, stream>>>(ei, ew, offp, cur, tok, wg);
  stage1_k<<<dim3(DFF / 128, MT1), 512, 98304, stream>>>(xb, w1t, w2t, hb, tok, offp);
  stage2_k<<<dim3(DMODEL / 256, PPAD / 128), 512, 73728, stream>>>(hb, w3t, out, tok, wg, offp);
}

// Round 12
// 706.219 us; speedup vs baseline: 1.1894x; 1.1413x over previous
//
#include <hip/hip_runtime.h>
#include <hip/hip_bf16.h>

typedef __attribute__((ext_vector_type(8))) short short8;
typedef __attribute__((ext_vector_type(4))) float f32x4;
typedef unsigned short u16;
typedef unsigned int u32;

#define NTOK   8192
#define DMODEL 1024
#define DFF    4096
#define NEXP   8
#define NPAIR  (NTOK * 2)
#define PADM   256            // per-expert padding
#define MT1    72             // ceil((16384 + 8*255)/256)
#define PPAD   (MT1 * PADM)   // 18432

// ---- workspace layout (bytes) ----
#define OFF_XB   0ull
#define OFF_W1T  (OFF_XB  + (size_t)NTOK * DMODEL * 2)
#define OFF_W2T  (OFF_W1T + (size_t)NEXP * DFF * DMODEL * 2)
#define OFF_W3T  (OFF_W2T + (size_t)NEXP * DFF * DMODEL * 2)
#define OFF_H    (OFF_W3T + (size_t)NEXP * DMODEL * DFF * 2)
#define OFF_TOK  (OFF_H   + (size_t)PPAD * DFF * 2)
#define OFF_WGT  (OFF_TOK + (size_t)PPAD * 4)
#define OFF_OFFP (OFF_WGT + (size_t)PPAD * 4)
#define WS_END   (OFF_OFFP + 64)

#define GLOAD16(gp, lp)                                                        \
  __builtin_amdgcn_global_load_lds(                                            \
      (const __attribute__((address_space(1))) u32*)(gp),                      \
      (__attribute__((address_space(3))) u32*)(lp), 16, 0, 0)

__device__ __forceinline__ u16 f2bu(float f) {
  __hip_bfloat16 b = __float2bfloat16(f);
  return __builtin_bit_cast(u16, b);
}

// ---------------- conversion kernels ----------------

__global__ __launch_bounds__(256) void cvt_x_k(const float* __restrict__ x,
                                               u16* __restrict__ xb) {
  int i = blockIdx.x * 256 + threadIdx.x;
  float4 v = ((const float4*)x)[i];
  unsigned long long pk = (unsigned long long)f2bu(v.x) |
                          ((unsigned long long)f2bu(v.y) << 16) |
                          ((unsigned long long)f2bu(v.z) << 32) |
                          ((unsigned long long)f2bu(v.w) << 48);
  ((unsigned long long*)xb)[i] = pk;
}

// Fused weight transpose+convert: [R][C] fp32 -> [C][R] bf16 for w1,w2,w3.
// blockIdx.y in [0,24): 0-7 w1 experts, 8-15 w2, 16-23 w3. Both shapes give
// exactly 256 tiles/expert (tile = 256 src-rows x 64 cols).
__global__ __launch_bounds__(256) void wcvt_k(const float* __restrict__ w1,
                                              const float* __restrict__ w2,
                                              const float* __restrict__ w3,
                                              u16* __restrict__ w1t,
                                              u16* __restrict__ w2t,
                                              u16* __restrict__ w3t) {
  const int z = blockIdx.y;
  const float* src; u16* dst; int R, C, tx, ty;
  if (z < 16) {
    R = DMODEL; C = DFF;
    int e = z & 7;
    src = ((z < 8) ? w1 : w2) + (size_t)e * R * C;
    dst = ((z < 8) ? w1t : w2t) + (size_t)e * R * C;
    tx = blockIdx.x & 63; ty = blockIdx.x >> 6;     // 64 x 4
  } else {
    R = DFF; C = DMODEL;
    int e = z - 16;
    src = w3 + (size_t)e * R * C;
    dst = w3t + (size_t)e * R * C;
    tx = blockIdx.x & 15; ty = blockIdx.x >> 4;     // 16 x 16
  }
  const int c0 = tx * 64, r0 = ty * 256;
  __shared__ u16 t[256][68];
  const int tid = threadIdx.x;
  const int cl = (tid & 15) * 4, rl = tid >> 4;
#pragma unroll
  for (int p = 0; p < 16; ++p) {
    int r = rl + p * 16;
    float4 v = *(const float4*)(src + (size_t)(r0 + r) * C + c0 + cl);
    unsigned long long pk = (unsigned long long)f2bu(v.x) |
                            ((unsigned long long)f2bu(v.y) << 16) |
                            ((unsigned long long)f2bu(v.z) << 32) |
                            ((unsigned long long)f2bu(v.w) << 48);
    *(unsigned long long*)&t[r][cl] = pk;
  }
  __syncthreads();
  const int c = tid >> 2, seg = tid & 3;   // 4 threads per output col
#pragma unroll
  for (int u = 0; u < 8; ++u) {
    int rbase = seg * 8 + u * 32;
    short8 o;
#pragma unroll
    for (int j = 0; j < 8; ++j) o[j] = (short)t[rbase + j][c];
    *(short8*)(dst + (size_t)(c0 + c) * R + r0 + rbase) = o;
  }
}

// ---------------- routing: init + count + scan + scatter, one block -------

__global__ __launch_bounds__(1024) void route_k(const int* __restrict__ ei,
                                                const float* __restrict__ ew,
                                                int* __restrict__ tok,
                                                float* __restrict__ wg,
                                                int* __restrict__ offp_g) {
  __shared__ int cnt[NEXP], offp[NEXP + 1], cur[NEXP];
  const int tid = threadIdx.x;
  if (tid < NEXP) { cnt[tid] = 0; cur[tid] = 0; }
  __syncthreads();
  // init padded token list (padded rows: tok=0, wg=0 -> contribute nothing)
  for (int i = tid; i < PPAD; i += 1024) { tok[i] = 0; wg[i] = 0.f; }
  // count via per-wave ballot histogram
  for (int i = tid; i < NPAIR; i += 1024) {
    int e = ei[i];
#pragma unroll
    for (int x = 0; x < NEXP; ++x) {
      unsigned long long m = __ballot(e == x);
      if ((tid & 63) == 0 && m) atomicAdd(&cnt[x], (int)__popcll(m));
    }
  }
  __syncthreads();
  if (tid == 0) {
    int a = 0;
#pragma unroll
    for (int e = 0; e < NEXP; ++e) { offp[e] = a; a += (cnt[e] + PADM - 1) & ~(PADM - 1); }
    offp[NEXP] = a;
  }
  __syncthreads();
  for (int i = tid; i < NPAIR; i += 1024) {
    int e = ei[i];
    int p = offp[e] + atomicAdd(&cur[e], 1);
    tok[p] = i >> 1;
    wg[p] = ew[i];
  }
  if (tid <= NEXP) offp_g[tid] = offp[tid];
}

// ---------------- stage 1: h = silu(x@W1) * (x@W2), grouped ----------------
// r5 kernel verbatim (best measured: 321 us, MfmaUtil 40.5%, 0 conflicts).
// 3-buffer, BK=32, counted vmcnt(4), 1 barrier/step, MFMA 16x16x32.

#define S1_BUF 16384   // u16 per buffer: A 8192 | B1 4096 | B2 4096
#define S1_NK  32      // 1024 / 32

__global__ __launch_bounds__(512, 2) void stage1_k(const u16* __restrict__ xb,
                                                   const u16* __restrict__ w1t,
                                                   const u16* __restrict__ w2t,
                                                   u16* __restrict__ h,
                                                   const int* __restrict__ tok,
                                                   const int* __restrict__ offp) {
  extern __shared__ __align__(16) u16 lds[];   // 3 * 32 KB = 98304 B
  const int r0 = blockIdx.y * PADM;
  if (r0 >= offp[NEXP]) return;
  int e = 0;
#pragma unroll
  for (int q = 0; q < 7; ++q) e += (offp[e + 1] <= r0) ? 1 : 0;
  const int n0 = blockIdx.x * 128;
  const int tid = threadIdx.x;
  const int lane = tid & 63, w = tid >> 6;
  const int wm = w >> 2, wn = w & 3;

  const int sl = lane & 3, rl = lane >> 2;
  const u16* aga[2];
  int adb[2];
#pragma unroll
  for (int j = 0; j < 2; ++j) {
    int row = w * 32 + j * 16 + rl;
    int t = tok[r0 + row];
    aga[j] = xb + (size_t)t * DMODEL + ((sl ^ ((row >> 1) & 3)) << 3);
    adb[j] = (w * 32 + j * 16) * 32;
  }
  const u16* w1e = w1t + (size_t)e * DFF * DMODEL;
  const u16* w2e = w2t + (size_t)e * DFF * DMODEL;
  const u16* bg1; const u16* bg2;
  int bdb;
  {
    int row = w * 16 + rl;
    size_t ro = (size_t)(n0 + row) * DMODEL + ((sl ^ ((row >> 1) & 3)) << 3);
    bg1 = w1e + ro; bg2 = w2e + ro;
    bdb = (w * 16) * 32;
  }

  int aoff[8], boff[2];
  {
    int ks = lane >> 4;
#pragma unroll
    for (int mi = 0; mi < 8; ++mi) {
      int row = wm * 128 + mi * 16 + (lane & 15);
      aoff[mi] = row * 32 + ((ks ^ ((row >> 1) & 3)) << 3);
    }
#pragma unroll
    for (int ni = 0; ni < 2; ++ni) {
      int col = wn * 32 + ni * 16 + (lane & 15);
      boff[ni] = col * 32 + ((ks ^ ((col >> 1) & 3)) << 3);
    }
  }

  f32x4 accg[8][2], accv[8][2];
  const f32x4 zero = {0.f, 0.f, 0.f, 0.f};
#pragma unroll
  for (int mi = 0; mi < 8; ++mi)
#pragma unroll
    for (int ni = 0; ni < 2; ++ni) { accg[mi][ni] = zero; accv[mi][ni] = zero; }

#define S1_ISSUE(Q, KO)                                                        \
  do {                                                                         \
    GLOAD16(aga[0] + (KO), (Q) + adb[0]);                                      \
    GLOAD16(aga[1] + (KO), (Q) + adb[1]);                                      \
    GLOAD16(bg1 + (KO), (Q) + 8192 + bdb);                                     \
    GLOAD16(bg2 + (KO), (Q) + 12288 + bdb);                                    \
  } while (0)

  S1_ISSUE(lds, 0);
  S1_ISSUE(lds + S1_BUF, 32);
  asm volatile("s_waitcnt vmcnt(4)" ::: "memory");
  __builtin_amdgcn_s_barrier();
  __builtin_amdgcn_sched_barrier(0);

#define S1_STEP(P, KC, ISSUE)                                                  \
  {                                                                            \
    const u16* Ab  = lds + (P) * S1_BUF;                                       \
    const u16* B1b = Ab + 8192;                                                \
    const u16* B2b = Ab + 12288;                                               \
    short8 af[8], b1f[2], b2f[2];                                              \
    _Pragma("unroll") for (int mi = 0; mi < 8; ++mi)                           \
      af[mi] = *(const short8*)(Ab + aoff[mi]);                                \
    _Pragma("unroll") for (int ni = 0; ni < 2; ++ni) {                         \
      b1f[ni] = *(const short8*)(B1b + boff[ni]);                              \
      b2f[ni] = *(const short8*)(B2b + boff[ni]);                              \
    }                                                                          \
    if (ISSUE) S1_ISSUE(lds + (((P) + 2) % 3) * S1_BUF, ((KC) + 2) * 32);      \
    __builtin_amdgcn_s_setprio(1);                                             \
    _Pragma("unroll") for (int mi = 0; mi < 8; ++mi)                           \
      _Pragma("unroll") for (int ni = 0; ni < 2; ++ni) {                       \
        accg[mi][ni] = __builtin_amdgcn_mfma_f32_16x16x32_bf16(                \
            af[mi], b1f[ni], accg[mi][ni], 0, 0, 0);                           \
        accv[mi][ni] = __builtin_amdgcn_mfma_f32_16x16x32_bf16(                \
            af[mi], b2f[ni], accv[mi][ni], 0, 0, 0);                           \
      }                                                                        \
    __builtin_amdgcn_s_setprio(0);                                             \
    if (ISSUE) asm volatile("s_waitcnt vmcnt(4)" ::: "memory");                \
    else       asm volatile("s_waitcnt vmcnt(0)" ::: "memory");                \
    __builtin_amdgcn_s_barrier();                                              \
    __builtin_amdgcn_sched_barrier(0);                                         \
  }

  for (int kc = 0; kc < S1_NK - 2; kc += 3) {
    S1_STEP(0, kc, 1)
    S1_STEP(1, kc + 1, 1)
    S1_STEP(2, kc + 2, 1)
  }
  S1_STEP(0, S1_NK - 2, 0)
  S1_STEP(1, S1_NK - 1, 0)
#undef S1_STEP
#undef S1_ISSUE

  const int prow = r0 + wm * 128 + ((lane >> 4) << 2);
  const int pcol = n0 + wn * 32 + (lane & 15);
#pragma unroll
  for (int mi = 0; mi < 8; ++mi)
#pragma unroll
    for (int ni = 0; ni < 2; ++ni)
#pragma unroll
      for (int j = 0; j < 4; ++j) {
        float g = accg[mi][ni][j];
        float v = accv[mi][ni][j];
        float s = g / (1.f + __expf(-g));
        h[(size_t)(prow + mi * 16 + j) * DFF + (pcol + ni * 16)] = f2bu(s * v);
      }
}

// ---------------- stage 2: out += p * (h @ W3), grouped ----------------
// r11 verbatim: tile 128x256, BK=32, 3-buffer counted vmcnt(3), 2 blocks/CU,
// bijective XCD-chunked swizzle (576 = 8*72 exact).

#define S2_BUF 12288   // u16 per buffer: A 4096 (128x32) | B 8192 (256x32)
#define S2_NK  128     // 4096 / 32

__global__ __launch_bounds__(512, 4) void stage2_k(const u16* __restrict__ h,
                                                   const u16* __restrict__ w3t,
                                                   float* __restrict__ out,
                                                   const int* __restrict__ tok,
                                                   const float* __restrict__ wg,
                                                   const int* __restrict__ offp) {
  extern __shared__ __align__(16) u16 lds[];   // 3 * 24576 B = 73728 B
  const int orig = blockIdx.y * 4 + blockIdx.x;     // gridDim = (4, 144)
  const int wgid = (orig & 7) * 72 + (orig >> 3);
  const int bx = wgid & 3, by = wgid >> 2;
  const int r0 = by * 128;
  if (r0 >= offp[NEXP]) return;
  int e = 0;
#pragma unroll
  for (int q = 0; q < 7; ++q) e += (offp[e + 1] <= r0) ? 1 : 0;
  const int n0 = bx * 256;
  const int tid = threadIdx.x;
  const int lane = tid & 63, w = tid >> 6;
  const int wm = w >> 2, wn = w & 3;

  const int sl = lane & 3, rl = lane >> 2;
  const u16* aga;
  int adb;
  {
    int row = w * 16 + rl;
    aga = h + (size_t)(r0 + row) * DFF + ((sl ^ ((row >> 1) & 3)) << 3);
    adb = (w * 16) * 32;
  }
  const u16* w3e = w3t + (size_t)e * DMODEL * DFF;
  const u16* bga[2];
  int bdb[2];
#pragma unroll
  for (int j = 0; j < 2; ++j) {
    int row = w * 32 + j * 16 + rl;
    bga[j] = w3e + (size_t)(n0 + row) * DFF + ((sl ^ ((row >> 1) & 3)) << 3);
    bdb[j] = 4096 + (w * 32 + j * 16) * 32;
  }

  int aoff[4], boff[4];
  {
    int ks = lane >> 4;
#pragma unroll
    for (int mi = 0; mi < 4; ++mi) {
      int row = wm * 64 + mi * 16 + (lane & 15);
      aoff[mi] = row * 32 + ((ks ^ ((row >> 1) & 3)) << 3);
    }
#pragma unroll
    for (int ni = 0; ni < 4; ++ni) {
      int col = wn * 64 + ni * 16 + (lane & 15);
      boff[ni] = 4096 + col * 32 + ((ks ^ ((col >> 1) & 3)) << 3);
    }
  }

  f32x4 acc[4][4];
  const f32x4 zero = {0.f, 0.f, 0.f, 0.f};
#pragma unroll
  for (int mi = 0; mi < 4; ++mi)
#pragma unroll
    for (int ni = 0; ni < 4; ++ni) acc[mi][ni] = zero;

#define S2_ISSUE(Q, KO)                                                        \
  do {                                                                         \
    GLOAD16(aga + (KO), (Q) + adb);                                            \
    GLOAD16(bga[0] + (KO), (Q) + bdb[0]);                                      \
    GLOAD16(bga[1] + (KO), (Q) + bdb[1]);                                      \
  } while (0)

  S2_ISSUE(lds, 0);
  S2_ISSUE(lds + S2_BUF, 32);
  asm volatile("s_waitcnt vmcnt(3)" ::: "memory");
  __builtin_amdgcn_s_barrier();
  __builtin_amdgcn_sched_barrier(0);

#define S2_STEP(P, KC, ISSUE)                                                  \
  {                                                                            \
    const u16* Qb = lds + (P) * S2_BUF;                                        \
    short8 af[4], bf[4];                                                       \
    _Pragma("unroll") for (int mi = 0; mi < 4; ++mi)                           \
      af[mi] = *(const short8*)(Qb + aoff[mi]);                                \
    _Pragma("unroll") for (int ni = 0; ni < 4; ++ni)                           \
      bf[ni] = *(const short8*)(Qb + boff[ni]);                                \
    if (ISSUE) S2_ISSUE(lds + (((P) + 2) % 3) * S2_BUF, ((KC) + 2) * 32);      \
    __builtin_amdgcn_s_setprio(1);                                             \
    _Pragma("unroll") for (int mi = 0; mi < 4; ++mi)                           \
      _Pragma("unroll") for (int ni = 0; ni < 4; ++ni)                         \
        acc[mi][ni] = __builtin_amdgcn_mfma_f32_16x16x32_bf16(                 \
            af[mi], bf[ni], acc[mi][ni], 0, 0, 0);                             \
    __builtin_amdgcn_s_setprio(0);                                             \
    if (ISSUE) asm volatile("s_waitcnt vmcnt(3)" ::: "memory");                \
    else       asm volatile("s_waitcnt vmcnt(0)" ::: "memory");                \
    __builtin_amdgcn_s_barrier();                                              \
    __builtin_amdgcn_sched_barrier(0);                                         \
  }

  for (int kc = 0; kc < S2_NK - 2; kc += 3) {
    S2_STEP(0, kc, 1)
    S2_STEP(1, kc + 1, 1)
    S2_STEP(2, kc + 2, 1)
  }
  S2_STEP(0, S2_NK - 2, 0)
  S2_STEP(1, S2_NK - 1, 0)
#undef S2_STEP
#undef S2_ISSUE

  const int prow = r0 + wm * 64 + ((lane >> 4) << 2);
  const int pcolb = n0 + wn * 64 + (lane & 15);
#pragma unroll
  for (int mi = 0; mi < 4; ++mi)
#pragma unroll
    for (int j = 0; j < 4; ++j) {
      int pos = prow + mi * 16 + j;
      float p = wg[pos];
      if (p != 0.f) {
        int t = tok[pos];
#pragma unroll
        for (int ni = 0; ni < 4; ++ni)
          atomicAdd(&out[(size_t)t * DMODEL + pcolb + ni * 16], p * acc[mi][ni][j]);
      }
    }
}

// ---------------- launch ----------------

extern "C" void kernel_launch(void* const* d_in, const int* in_sizes, int n_in,
                              void* d_out, int out_size, void* d_ws, size_t ws_size,
                              hipStream_t stream) {
  (void)in_sizes; (void)n_in;
  const float* x  = (const float*)d_in[0];
  const int*   ei = (const int*)d_in[1];
  const float* ew = (const float*)d_in[2];
  const float* w1 = (const float*)d_in[3];
  const float* w2 = (const float*)d_in[4];
  const float* w3 = (const float*)d_in[5];
  float* out = (float*)d_out;
  char* ws = (char*)d_ws;

  hipMemsetAsync(out, 0, (size_t)out_size * sizeof(float), stream);
  if (ws_size < WS_END) return;   // ws too small: leave zeros (diagnosable absmax)

  u16* xb   = (u16*)(ws + OFF_XB);
  u16* w1t  = (u16*)(ws + OFF_W1T);
  u16* w2t  = (u16*)(ws + OFF_W2T);
  u16* w3t  = (u16*)(ws + OFF_W3T);
  u16* hb   = (u16*)(ws + OFF_H);
  int* tok  = (int*)(ws + OFF_TOK);
  float* wg = (float*)(ws + OFF_WGT);
  int* offp = (int*)(ws + OFF_OFFP);

  hipFuncSetAttribute(reinterpret_cast<const void*>(stage1_k),
                      hipFuncAttributeMaxDynamicSharedMemorySize, 98304);
  hipFuncSetAttribute(reinterpret_cast<const void*>(stage2_k),
                      hipFuncAttributeMaxDynamicSharedMemorySize, 73728);

  cvt_x_k<<<dim3(NTOK * DMODEL / 4 / 256), 256, 0, stream>>>(x, xb);
  wcvt_k<<<dim3(256, 24), 256, 0, stream>>>(w1, w2, w3, w1t, w2t, w3t);
  route_k<<<dim3(1), 1024, 0, stream>>>(ei, ew, tok, wg, offp);
  stage1_k<<<dim3(DFF / 128, MT1), 512, 98304, stream>>>(xb, w1t, w2t, hb, tok, offp);
  stage2_k<<<dim3(DMODEL / 256, PPAD / 128), 512, 73728, stream>>>(hb, w3t, out, tok, wg, offp);
}

// Round 13
// 694.834 us; speedup vs baseline: 1.2089x; 1.0164x over previous
//
#include <hip/hip_runtime.h>
#include <hip/hip_bf16.h>

typedef __attribute__((ext_vector_type(8))) short short8;
typedef __attribute__((ext_vector_type(4))) float f32x4;
typedef unsigned short u16;
typedef unsigned int u32;

#define NTOK   8192
#define DMODEL 1024
#define DFF    4096
#define NEXP   8
#define NPAIR  (NTOK * 2)
#define PADM   256            // per-expert padding
#define MT1    72             // ceil((16384 + 8*255)/256)
#define PPAD   (MT1 * PADM)   // 18432

// ---- workspace layout (bytes) ----
#define OFF_XB   0ull
#define OFF_W1T  (OFF_XB  + (size_t)NTOK * DMODEL * 2)
#define OFF_W2T  (OFF_W1T + (size_t)NEXP * DFF * DMODEL * 2)
#define OFF_W3T  (OFF_W2T + (size_t)NEXP * DFF * DMODEL * 2)
#define OFF_H    (OFF_W3T + (size_t)NEXP * DMODEL * DFF * 2)
#define OFF_TOK  (OFF_H   + (size_t)PPAD * DFF * 2)
#define OFF_WGT  (OFF_TOK + (size_t)PPAD * 4)
#define OFF_OFFP (OFF_WGT + (size_t)PPAD * 4)
#define WS_END   (OFF_OFFP + 64)

#define GLOAD16(gp, lp)                                                        \
  __builtin_amdgcn_global_load_lds(                                            \
      (const __attribute__((address_space(1))) u32*)(gp),                      \
      (__attribute__((address_space(3))) u32*)(lp), 16, 0, 0)

__device__ __forceinline__ u16 f2bu(float f) {
  __hip_bfloat16 b = __float2bfloat16(f);
  return __builtin_bit_cast(u16, b);
}

// ---------------- conversion kernels ----------------

__global__ __launch_bounds__(256) void cvt_x_k(const float* __restrict__ x,
                                               u16* __restrict__ xb) {
  int i = blockIdx.x * 256 + threadIdx.x;
  float4 v = ((const float4*)x)[i];
  unsigned long long pk = (unsigned long long)f2bu(v.x) |
                          ((unsigned long long)f2bu(v.y) << 16) |
                          ((unsigned long long)f2bu(v.z) << 32) |
                          ((unsigned long long)f2bu(v.w) << 48);
  ((unsigned long long*)xb)[i] = pk;
}

// Fused weight transpose+convert: [R][C] fp32 -> [C][R] bf16 for w1,w2,w3.
__global__ __launch_bounds__(256) void wcvt_k(const float* __restrict__ w1,
                                              const float* __restrict__ w2,
                                              const float* __restrict__ w3,
                                              u16* __restrict__ w1t,
                                              u16* __restrict__ w2t,
                                              u16* __restrict__ w3t) {
  const int z = blockIdx.y;
  const float* src; u16* dst; int R, C, tx, ty;
  if (z < 16) {
    R = DMODEL; C = DFF;
    int e = z & 7;
    src = ((z < 8) ? w1 : w2) + (size_t)e * R * C;
    dst = ((z < 8) ? w1t : w2t) + (size_t)e * R * C;
    tx = blockIdx.x & 63; ty = blockIdx.x >> 6;     // 64 x 4
  } else {
    R = DFF; C = DMODEL;
    int e = z - 16;
    src = w3 + (size_t)e * R * C;
    dst = w3t + (size_t)e * R * C;
    tx = blockIdx.x & 15; ty = blockIdx.x >> 4;     // 16 x 16
  }
  const int c0 = tx * 64, r0 = ty * 256;
  __shared__ u16 t[256][68];
  const int tid = threadIdx.x;
  const int cl = (tid & 15) * 4, rl = tid >> 4;
#pragma unroll
  for (int p = 0; p < 16; ++p) {
    int r = rl + p * 16;
    float4 v = *(const float4*)(src + (size_t)(r0 + r) * C + c0 + cl);
    unsigned long long pk = (unsigned long long)f2bu(v.x) |
                            ((unsigned long long)f2bu(v.y) << 16) |
                            ((unsigned long long)f2bu(v.z) << 32) |
                            ((unsigned long long)f2bu(v.w) << 48);
    *(unsigned long long*)&t[r][cl] = pk;
  }
  __syncthreads();
  const int c = tid >> 2, seg = tid & 3;
#pragma unroll
  for (int u = 0; u < 8; ++u) {
    int rbase = seg * 8 + u * 32;
    short8 o;
#pragma unroll
    for (int j = 0; j < 8; ++j) o[j] = (short)t[rbase + j][c];
    *(short8*)(dst + (size_t)(c0 + c) * R + r0 + rbase) = o;
  }
}

// ---------------- routing: init + count + scan + scatter, one block -------

__global__ __launch_bounds__(1024) void route_k(const int* __restrict__ ei,
                                                const float* __restrict__ ew,
                                                int* __restrict__ tok,
                                                float* __restrict__ wg,
                                                int* __restrict__ offp_g) {
  __shared__ int cnt[NEXP], offp[NEXP + 1], cur[NEXP];
  const int tid = threadIdx.x;
  if (tid < NEXP) { cnt[tid] = 0; cur[tid] = 0; }
  __syncthreads();
  for (int i = tid; i < PPAD; i += 1024) { tok[i] = 0; wg[i] = 0.f; }
  for (int i = tid; i < NPAIR; i += 1024) {
    int e = ei[i];
#pragma unroll
    for (int x = 0; x < NEXP; ++x) {
      unsigned long long m = __ballot(e == x);
      if ((tid & 63) == 0 && m) atomicAdd(&cnt[x], (int)__popcll(m));
    }
  }
  __syncthreads();
  if (tid == 0) {
    int a = 0;
#pragma unroll
    for (int e = 0; e < NEXP; ++e) { offp[e] = a; a += (cnt[e] + PADM - 1) & ~(PADM - 1); }
    offp[NEXP] = a;
  }
  __syncthreads();
  for (int i = tid; i < NPAIR; i += 1024) {
    int e = ei[i];
    int p = offp[e] + atomicAdd(&cur[e], 1);
    tok[p] = i >> 1;
    wg[p] = ew[i];
  }
  if (tid <= NEXP) offp_g[tid] = offp[tid];
}

// ---------------- stage 1: h = silu(x@W1) * (x@W2), grouped ----------------
// r5 skeleton resized for 2-blocks/CU co-residency: tile 128x128, BK=32,
// 3-buffer counted vmcnt(3), 1 barrier/step. LDS 3 x 24 KB = 72 KB ->
// 2 blocks/CU (144 KB); launch_bounds(512,4) caps VGPR at 128 (acc 64 +
// frags 32 + addr ~20). While one block sits at its barrier/vmcnt, the
// other block's MFMAs issue (m114 cross-block overlap). Grid (32,144) =
// 4608 blocks = 9 exact rounds. Swizzle formulas identical to r5.

#define S1_BUF 12288   // u16 per buffer: A 4096 | B1 4096 | B2 4096
#define S1_NK  32      // 1024 / 32

__global__ __launch_bounds__(512, 4) void stage1_k(const u16* __restrict__ xb,
                                                   const u16* __restrict__ w1t,
                                                   const u16* __restrict__ w2t,
                                                   u16* __restrict__ h,
                                                   const int* __restrict__ tok,
                                                   const int* __restrict__ offp) {
  extern __shared__ __align__(16) u16 lds[];   // 3 * 24576 B = 73728 B
  const int r0 = blockIdx.y * 128;
  if (r0 >= offp[NEXP]) return;
  int e = 0;
#pragma unroll
  for (int q = 0; q < 7; ++q) e += (offp[e + 1] <= r0) ? 1 : 0;
  const int n0 = blockIdx.x * 128;
  const int tid = threadIdx.x;
  const int lane = tid & 63, w = tid >> 6;
  const int wm = w >> 2, wn = w & 3;

  const int sl = lane & 3, rl = lane >> 2;
  // A staging: 128 token-rows, 1 issue/thread (wave w: rows w*16..w*16+15)
  const u16* aga;
  int adb;
  {
    int row = w * 16 + rl;
    int t = tok[r0 + row];
    aga = xb + (size_t)t * DMODEL + ((sl ^ ((row >> 1) & 3)) << 3);
    adb = (w * 16) * 32;
  }
  // B staging: 128 ff-cols each for w1,w2; 1 issue/thread each
  const u16* w1e = w1t + (size_t)e * DFF * DMODEL;
  const u16* w2e = w2t + (size_t)e * DFF * DMODEL;
  const u16* bg1; const u16* bg2;
  int bdb;
  {
    int row = w * 16 + rl;
    size_t ro = (size_t)(n0 + row) * DMODEL + ((sl ^ ((row >> 1) & 3)) << 3);
    bg1 = w1e + ro; bg2 = w2e + ro;
    bdb = (w * 16) * 32;
  }

  int aoff[4], boff[2];
  {
    int ks = lane >> 4;
#pragma unroll
    for (int mi = 0; mi < 4; ++mi) {
      int row = wm * 64 + mi * 16 + (lane & 15);
      aoff[mi] = row * 32 + ((ks ^ ((row >> 1) & 3)) << 3);
    }
#pragma unroll
    for (int ni = 0; ni < 2; ++ni) {
      int col = wn * 32 + ni * 16 + (lane & 15);
      boff[ni] = col * 32 + ((ks ^ ((col >> 1) & 3)) << 3);
    }
  }

  f32x4 accg[4][2], accv[4][2];
  const f32x4 zero = {0.f, 0.f, 0.f, 0.f};
#pragma unroll
  for (int mi = 0; mi < 4; ++mi)
#pragma unroll
    for (int ni = 0; ni < 2; ++ni) { accg[mi][ni] = zero; accv[mi][ni] = zero; }

#define S1_ISSUE(Q, KO)                                                        \
  do {                                                                         \
    GLOAD16(aga + (KO), (Q) + adb);                                            \
    GLOAD16(bg1 + (KO), (Q) + 4096 + bdb);                                     \
    GLOAD16(bg2 + (KO), (Q) + 8192 + bdb);                                     \
  } while (0)

  S1_ISSUE(lds, 0);
  S1_ISSUE(lds + S1_BUF, 32);
  asm volatile("s_waitcnt vmcnt(3)" ::: "memory");
  __builtin_amdgcn_s_barrier();
  __builtin_amdgcn_sched_barrier(0);

#define S1_STEP(P, KC, ISSUE)                                                  \
  {                                                                            \
    const u16* Ab  = lds + (P) * S1_BUF;                                       \
    const u16* B1b = Ab + 4096;                                                \
    const u16* B2b = Ab + 8192;                                                \
    short8 af[4], b1f[2], b2f[2];                                              \
    _Pragma("unroll") for (int mi = 0; mi < 4; ++mi)                           \
      af[mi] = *(const short8*)(Ab + aoff[mi]);                                \
    _Pragma("unroll") for (int ni = 0; ni < 2; ++ni) {                         \
      b1f[ni] = *(const short8*)(B1b + boff[ni]);                              \
      b2f[ni] = *(const short8*)(B2b + boff[ni]);                              \
    }                                                                          \
    if (ISSUE) S1_ISSUE(lds + (((P) + 2) % 3) * S1_BUF, ((KC) + 2) * 32);      \
    __builtin_amdgcn_s_setprio(1);                                             \
    _Pragma("unroll") for (int mi = 0; mi < 4; ++mi)                           \
      _Pragma("unroll") for (int ni = 0; ni < 2; ++ni) {                       \
        accg[mi][ni] = __builtin_amdgcn_mfma_f32_16x16x32_bf16(                \
            af[mi], b1f[ni], accg[mi][ni], 0, 0, 0);                           \
        accv[mi][ni] = __builtin_amdgcn_mfma_f32_16x16x32_bf16(                \
            af[mi], b2f[ni], accv[mi][ni], 0, 0, 0);                           \
      }                                                                        \
    __builtin_amdgcn_s_setprio(0);                                             \
    if (ISSUE) asm volatile("s_waitcnt vmcnt(3)" ::: "memory");                \
    else       asm volatile("s_waitcnt vmcnt(0)" ::: "memory");                \
    __builtin_amdgcn_s_barrier();                                              \
    __builtin_amdgcn_sched_barrier(0);                                         \
  }

  for (int kc = 0; kc < S1_NK - 2; kc += 3) {
    S1_STEP(0, kc, 1)
    S1_STEP(1, kc + 1, 1)
    S1_STEP(2, kc + 2, 1)
  }
  S1_STEP(0, S1_NK - 2, 0)
  S1_STEP(1, S1_NK - 1, 0)
#undef S1_STEP
#undef S1_ISSUE

  const int prow = r0 + wm * 64 + ((lane >> 4) << 2);
  const int pcol = n0 + wn * 32 + (lane & 15);
#pragma unroll
  for (int mi = 0; mi < 4; ++mi)
#pragma unroll
    for (int ni = 0; ni < 2; ++ni)
#pragma unroll
      for (int j = 0; j < 4; ++j) {
        float g = accg[mi][ni][j];
        float v = accv[mi][ni][j];
        float s = g / (1.f + __expf(-g));
        h[(size_t)(prow + mi * 16 + j) * DFF + (pcol + ni * 16)] = f2bu(s * v);
      }
}

// ---------------- stage 2: out += p * (h @ W3), grouped ----------------
// r11 verbatim: tile 128x256, BK=32, 3-buffer counted vmcnt(3), 2 blocks/CU,
// bijective XCD-chunked swizzle (576 = 8*72 exact).

#define S2_BUF 12288   // u16 per buffer: A 4096 (128x32) | B 8192 (256x32)
#define S2_NK  128     // 4096 / 32

__global__ __launch_bounds__(512, 4) void stage2_k(const u16* __restrict__ h,
                                                   const u16* __restrict__ w3t,
                                                   float* __restrict__ out,
                                                   const int* __restrict__ tok,
                                                   const float* __restrict__ wg,
                                                   const int* __restrict__ offp) {
  extern __shared__ __align__(16) u16 lds[];   // 3 * 24576 B = 73728 B
  const int orig = blockIdx.y * 4 + blockIdx.x;     // gridDim = (4, 144)
  const int wgid = (orig & 7) * 72 + (orig >> 3);
  const int bx = wgid & 3, by = wgid >> 2;
  const int r0 = by * 128;
  if (r0 >= offp[NEXP]) return;
  int e = 0;
#pragma unroll
  for (int q = 0; q < 7; ++q) e += (offp[e + 1] <= r0) ? 1 : 0;
  const int n0 = bx * 256;
  const int tid = threadIdx.x;
  const int lane = tid & 63, w = tid >> 6;
  const int wm = w >> 2, wn = w & 3;

  const int sl = lane & 3, rl = lane >> 2;
  const u16* aga;
  int adb;
  {
    int row = w * 16 + rl;
    aga = h + (size_t)(r0 + row) * DFF + ((sl ^ ((row >> 1) & 3)) << 3);
    adb = (w * 16) * 32;
  }
  const u16* w3e = w3t + (size_t)e * DMODEL * DFF;
  const u16* bga[2];
  int bdb[2];
#pragma unroll
  for (int j = 0; j < 2; ++j) {
    int row = w * 32 + j * 16 + rl;
    bga[j] = w3e + (size_t)(n0 + row) * DFF + ((sl ^ ((row >> 1) & 3)) << 3);
    bdb[j] = 4096 + (w * 32 + j * 16) * 32;
  }

  int aoff[4], boff[4];
  {
    int ks = lane >> 4;
#pragma unroll
    for (int mi = 0; mi < 4; ++mi) {
      int row = wm * 64 + mi * 16 + (lane & 15);
      aoff[mi] = row * 32 + ((ks ^ ((row >> 1) & 3)) << 3);
    }
#pragma unroll
    for (int ni = 0; ni < 4; ++ni) {
      int col = wn * 64 + ni * 16 + (lane & 15);
      boff[ni] = 4096 + col * 32 + ((ks ^ ((col >> 1) & 3)) << 3);
    }
  }

  f32x4 acc[4][4];
  const f32x4 zero = {0.f, 0.f, 0.f, 0.f};
#pragma unroll
  for (int mi = 0; mi < 4; ++mi)
#pragma unroll
    for (int ni = 0; ni < 4; ++ni) acc[mi][ni] = zero;

#define S2_ISSUE(Q, KO)                                                        \
  do {                                                                         \
    GLOAD16(aga + (KO), (Q) + adb);                                            \
    GLOAD16(bga[0] + (KO), (Q) + bdb[0]);                                      \
    GLOAD16(bga[1] + (KO), (Q) + bdb[1]);                                      \
  } while (0)

  S2_ISSUE(lds, 0);
  S2_ISSUE(lds + S2_BUF, 32);
  asm volatile("s_waitcnt vmcnt(3)" ::: "memory");
  __builtin_amdgcn_s_barrier();
  __builtin_amdgcn_sched_barrier(0);

#define S2_STEP(P, KC, ISSUE)                                                  \
  {                                                                            \
    const u16* Qb = lds + (P) * S2_BUF;                                        \
    short8 af[4], bf[4];                                                       \
    _Pragma("unroll") for (int mi = 0; mi < 4; ++mi)                           \
      af[mi] = *(const short8*)(Qb + aoff[mi]);                                \
    _Pragma("unroll") for (int ni = 0; ni < 4; ++ni)                           \
      bf[ni] = *(const short8*)(Qb + boff[ni]);                                \
    if (ISSUE) S2_ISSUE(lds + (((P) + 2) % 3) * S2_BUF, ((KC) + 2) * 32);      \
    __builtin_amdgcn_s_setprio(1);                                             \
    _Pragma("unroll") for (int mi = 0; mi < 4; ++mi)                           \
      _Pragma("unroll") for (int ni = 0; ni < 4; ++ni)                         \
        acc[mi][ni] = __builtin_amdgcn_mfma_f32_16x16x32_bf16(                 \
            af[mi], bf[ni], acc[mi][ni], 0, 0, 0);                             \
    __builtin_amdgcn_s_setprio(0);                                             \
    if (ISSUE) asm volatile("s_waitcnt vmcnt(3)" ::: "memory");                \
    else       asm volatile("s_waitcnt vmcnt(0)" ::: "memory");                \
    __builtin_amdgcn_s_barrier();                                              \
    __builtin_amdgcn_sched_barrier(0);                                         \
  }

  for (int kc = 0; kc < S2_NK - 2; kc += 3) {
    S2_STEP(0, kc, 1)
    S2_STEP(1, kc + 1, 1)
    S2_STEP(2, kc + 2, 1)
  }
  S2_STEP(0, S2_NK - 2, 0)
  S2_STEP(1, S2_NK - 1, 0)
#undef S2_STEP
#undef S2_ISSUE

  const int prow = r0 + wm * 64 + ((lane >> 4) << 2);
  const int pcolb = n0 + wn * 64 + (lane & 15);
#pragma unroll
  for (int mi = 0; mi < 4; ++mi)
#pragma unroll
    for (int j = 0; j < 4; ++j) {
      int pos = prow + mi * 16 + j;
      float p = wg[pos];
      if (p != 0.f) {
        int t = tok[pos];
#pragma unroll
        for (int ni = 0; ni < 4; ++ni)
          atomicAdd(&out[(size_t)t * DMODEL + pcolb + ni * 16], p * acc[mi][ni][j]);
      }
    }
}

// ---------------- launch ----------------

extern "C" void kernel_launch(void* const* d_in, const int* in_sizes, int n_in,
                              void* d_out, int out_size, void* d_ws, size_t ws_size,
                              hipStream_t stream) {
  (void)in_sizes; (void)n_in;
  const float* x  = (const float*)d_in[0];
  const int*   ei = (const int*)d_in[1];
  const float* ew = (const float*)d_in[2];
  const float* w1 = (const float*)d_in[3];
  const float* w2 = (const float*)d_in[4];
  const float* w3 = (const float*)d_in[5];
  float* out = (float*)d_out;
  char* ws = (char*)d_ws;

  hipMemsetAsync(out, 0, (size_t)out_size * sizeof(float), stream);
  if (ws_size < WS_END) return;   // ws too small: leave zeros (diagnosable absmax)

  u16* xb   = (u16*)(ws + OFF_XB);
  u16* w1t  = (u16*)(ws + OFF_W1T);
  u16* w2t  = (u16*)(ws + OFF_W2T);
  u16* w3t  = (u16*)(ws + OFF_W3T);
  u16* hb   = (u16*)(ws + OFF_H);
  int* tok  = (int*)(ws + OFF_TOK);
  float* wg = (float*)(ws + OFF_WGT);
  int* offp = (int*)(ws + OFF_OFFP);

  hipFuncSetAttribute(reinterpret_cast<const void*>(stage1_k),
                      hipFuncAttributeMaxDynamicSharedMemorySize, 73728);
  hipFuncSetAttribute(reinterpret_cast<const void*>(stage2_k),
                      hipFuncAttributeMaxDynamicSharedMemorySize, 73728);

  cvt_x_k<<<dim3(NTOK * DMODEL / 4 / 256), 256, 0, stream>>>(x, xb);
  wcvt_k<<<dim3(256, 24), 256, 0, stream>>>(w1, w2, w3, w1t, w2t, w3t);
  route_k<<<dim3(1), 1024, 0, stream>>>(ei, ew, tok, wg, offp);
  stage1_k<<<dim3(DFF / 128, PPAD / 128), 512, 73728, stream>>>(xb, w1t, w2t, hb, tok, offp);
  stage2_k<<<dim3(DMODEL / 256, PPAD / 128), 512, 73728, stream>>>(hb, w3t, out, tok, wg, offp);
}